// Round 7
// baseline (1597.002 us; speedup 1.0000x reference)
//
#include <hip/hip_runtime.h>
#include <hip/hip_bf16.h>
#include <cstdint>
#include <cstddef>

#define B_    64
#define N_    2048
#define E_    32768            // edges per graph
#define DIM_  64
#define K1_   1639
#define K2_   1312
#define NTOT  (B_ * N_)        // 131072
#define ETOT  (B_ * E_)        // 2097152
#define N2TOT (B_ * K1_)       // 104896
#define NCLS  6
#define PB_   8                // pooling blocks per graph
#define CHUNKS_ 8              // dst-chunks per graph
#define BCAP  8192             // bucket capacity (mean 4096, sd ~60)
#define SLICES_ 16             // edge slices per graph in k_bucket

static __device__ __forceinline__ void lds_addf(float* p, float v) {
    __hip_atomic_fetch_add(p, v, __ATOMIC_RELAXED, __HIP_MEMORY_SCOPE_WORKGROUP);
}

// ---------------- zero ints ----------------
__global__ void k_zero(int* a, int n) {
    int i = blockIdx.x * 256 + threadIdx.x;
    if (i < n) a[i] = 0;
}

// ---------------- bucket edges by (graph, dst-chunk); packed (dl<<12)|s_local --------------
// 16 slices per graph; graph = b&63 (XCD affinity g&7); one LDS append pass, coalesced out.
template<int STAGE>
__launch_bounds__(256)
__global__ void k_bucket(const int* src, const int* dst, const int* remap,
                         int* bcnt, unsigned int* blist) {
    const int NL   = (STAGE == 1) ? N_ : K1_;
    const int LSTR = (STAGE == 1) ? 256 : 205;
    __shared__ unsigned int lb[CHUNKS_][512];
    __shared__ int lc[CHUNKS_], lbase[CHUNKS_];
    int b = blockIdx.x;
    int g = b & 63, slice = b >> 6;
    int tid = threadIdx.x;
    if (tid < CHUNKS_) lc[tid] = 0;
    __syncthreads();
    const int ESL = E_ / SLICES_;              // 2048
    const int* sp = src + (size_t)g * E_ + slice * ESL;
    const int* dp = dst + (size_t)g * E_ + slice * ESL;
    int gbase = g * NL;
    for (int e = tid * 4; e < ESL; e += 1024) {
        int4 ss = *(const int4*)&sp[e];
        int4 dd = *(const int4*)&dp[e];
#pragma unroll
        for (int t = 0; t < 4; t++) {
            int s = (&ss.x)[t], d = (&dd.x)[t];
            if (STAGE == 2) {
                s = remap[s]; d = remap[d];
                if ((s | d) < 0) continue;
                s -= gbase; d -= gbase;
            } else {
                s &= (N_ - 1); d &= (N_ - 1);
            }
            int ch = d / LSTR;
            int dl = d - ch * LSTR;
            int p = atomicAdd(&lc[ch], 1);
            if (p < 512) lb[ch][p] = ((unsigned)dl << 12) | (unsigned)s;
        }
    }
    __syncthreads();
    if (tid < CHUNKS_) lbase[tid] = atomicAdd(&bcnt[g * CHUNKS_ + tid], min(lc[tid], 512));
    __syncthreads();
    for (int ch = 0; ch < CHUNKS_; ch++) {
        int n = min(lc[ch], 512), base0 = lbase[ch];
        unsigned int* out = blist + (size_t)(g * CHUNKS_ + ch) * BCAP + base0;
        for (int i = tid; i < n; i += 256)
            if (base0 + i < BCAP) out[i] = lb[ch][i];
    }
}

// ---------------- per-bucket degree count -> rsq, coef ----------------
// STAGE1: coef = rsq.  STAGE2: coef = vals * rsq.
template<int STAGE>
__launch_bounds__(256)
__global__ void k_degcoef(const int* bcnt, const unsigned int* blist,
                          const float* vals, float* rsq, float* coef) {
    const int NL   = (STAGE == 1) ? N_ : K1_;
    const int LSTR = (STAGE == 1) ? 256 : 205;
    __shared__ int cnt[256];
    int b = blockIdx.x;
    int g = b & 63, ch = b >> 6;
    int tid = threadIdx.x;
    cnt[tid] = 0;
    __syncthreads();
    int n = min(bcnt[g * CHUNKS_ + ch], BCAP);
    const unsigned int* bl = blist + (size_t)(g * CHUNKS_ + ch) * BCAP;
    for (int i = tid; i < n; i += 256) atomicAdd(&cnt[bl[i] >> 12], 1);
    __syncthreads();
    int lo = ch * LSTR;
    int nloc = min(LSTR, NL - lo);
    if (tid < nloc) {
        int node = g * NL + lo + tid;
        float rv = rsqrtf((float)(cnt[tid] + 1));
        rsq[node] = rv;
        coef[node] = (STAGE == 2) ? vals[node] * rv : rv;
    }
}

// ---------------- scatter-aggregate into LDS tile ----------------
// acc[dl][lane] += xrows[row(s)][lane] * coef[s]; then y = (acc + self) * rsq, coalesced.
// STAGE2: row(s) = sel[s] (physical stage-1 row).
template<int STAGE>
__launch_bounds__(256)
__global__ void k_scatagg(const float* xrows, const int* bcnt, const unsigned int* blist,
                          const float* rsq, const float* coef, const int* sel, float* y) {
    const int NL   = (STAGE == 1) ? N_ : K1_;
    constexpr int LSTR = (STAGE == 1) ? 256 : 205;
    __shared__ float acc[LSTR * DIM_];
    int b = blockIdx.x;
    int g = b & 63, ch = b >> 6;
    int tid = threadIdx.x, lane = tid & 63, wv = tid >> 6;
    for (int i = tid; i < LSTR * DIM_; i += 256) acc[i] = 0.f;
    __syncthreads();
    int n = min(bcnt[g * CHUNKS_ + ch], BCAP);
    const unsigned int* bl = blist + (size_t)(g * CHUNKS_ + ch) * BCAP;
    int gbase = g * NL;
    for (int base = wv * 64; base < n; base += 256) {
        int nch = min(64, n - base);
        unsigned pk = 0; int rowv = 0; float cv = 0.f;
        if (lane < nch) {
            pk = bl[base + lane];
            int snode = gbase + (int)(pk & 0xFFFu);
            rowv = (STAGE == 2) ? sel[snode] : snode;
            cv = coef[snode];
        }
        int i = 0;
        for (; i + 4 <= nch; i += 4) {
            int   r0 = __shfl(rowv, i),     r1 = __shfl(rowv, i+1),
                  r2 = __shfl(rowv, i+2),   r3 = __shfl(rowv, i+3);
            float c0 = __shfl(cv, i),       c1 = __shfl(cv, i+1),
                  c2 = __shfl(cv, i+2),     c3 = __shfl(cv, i+3);
            int   d0 = __shfl((int)(pk>>12), i),   d1 = __shfl((int)(pk>>12), i+1),
                  d2 = __shfl((int)(pk>>12), i+2), d3 = __shfl((int)(pk>>12), i+3);
            float v0 = xrows[(size_t)r0 * DIM_ + lane] * c0;
            float v1 = xrows[(size_t)r1 * DIM_ + lane] * c1;
            float v2 = xrows[(size_t)r2 * DIM_ + lane] * c2;
            float v3 = xrows[(size_t)r3 * DIM_ + lane] * c3;
            lds_addf(&acc[d0 * DIM_ + lane], v0);
            lds_addf(&acc[d1 * DIM_ + lane], v1);
            lds_addf(&acc[d2 * DIM_ + lane], v2);
            lds_addf(&acc[d3 * DIM_ + lane], v3);
        }
        for (; i < nch; i++) {
            int   rr = __shfl(rowv, i);
            float cc = __shfl(cv, i);
            int   dd = __shfl((int)(pk>>12), i);
            lds_addf(&acc[dd * DIM_ + lane], xrows[(size_t)rr * DIM_ + lane] * cc);
        }
    }
    __syncthreads();
    int lo = ch * LSTR;
    int nloc = min(LSTR, NL - lo);
    for (int nl = wv; nl < nloc; nl += 4) {
        int node = gbase + lo + nl;
        int srow = (STAGE == 2) ? sel[node] : node;
        float self = xrows[(size_t)srow * DIM_ + lane] * coef[node];
        y[(size_t)node * DIM_ + lane] = (acc[nl * DIM_ + lane] + self) * rsq[node];
    }
}

// ---------------- fused conv row-matmul + bias + ReLU + score (IN PLACE on y) ---------------
__launch_bounds__(256)
__global__ void k_convrow(float* y, const float* W, const float* bias, const float* pvec,
                          float* score, int rows) {
    __shared__ float Wl[DIM_ * DIM_];
    __shared__ float bl[DIM_], pl[DIM_];
    __shared__ float rpn;
    int tid = threadIdx.x;
    for (int i = tid; i < DIM_ * DIM_; i += 256) Wl[i] = W[i];
    if (tid < DIM_) { bl[tid] = bias[tid]; pl[tid] = pvec[tid]; }
    __syncthreads();
    if (tid == 0) {
        float s = 0.0f;
        for (int i = 0; i < DIM_; i++) s += pl[i] * pl[i];
        rpn = rsqrtf(s);
    }
    __syncthreads();
    int row = blockIdx.x * 256 + tid;
    if (row >= rows) return;
    float r[DIM_];
    float4* yp = (float4*)(y + (size_t)row * DIM_);
#pragma unroll
    for (int v = 0; v < 16; v++) {
        float4 q = yp[v];
        r[4*v] = q.x; r[4*v+1] = q.y; r[4*v+2] = q.z; r[4*v+3] = q.w;
    }
    float dot = 0.0f;
#pragma unroll
    for (int jb = 0; jb < 16; jb++) {
        float4 acc = make_float4(bl[jb*4], bl[jb*4+1], bl[jb*4+2], bl[jb*4+3]);
#pragma unroll
        for (int i = 0; i < DIM_; i++) {
            float4 w4 = *(const float4*)&Wl[i * DIM_ + jb * 4];
            acc.x += r[i] * w4.x; acc.y += r[i] * w4.y;
            acc.z += r[i] * w4.z; acc.w += r[i] * w4.w;
        }
        acc.x = fmaxf(acc.x, 0.f); acc.y = fmaxf(acc.y, 0.f);
        acc.z = fmaxf(acc.z, 0.f); acc.w = fmaxf(acc.w, 0.f);
        dot += acc.x * pl[jb*4] + acc.y * pl[jb*4+1] + acc.z * pl[jb*4+2] + acc.w * pl[jb*4+3];
        yp[jb] = acc;
    }
    score[row] = tanhf(dot * rpn);
}

// ---------------- exact top-K: 6-pass radix select, parallel suffix-sum bin scan ------------
template<int STAGE>
__launch_bounds__(256)
__global__ void k_select(const float* score, int* new_id, int* sel, float* vals) {
    const int Nin = (STAGE == 1) ? N_ : K1_;
    const int K   = (STAGE == 1) ? K1_ : K2_;
    __shared__ unsigned long long keys[N_];
    __shared__ int bins[256], ts[256];
    __shared__ unsigned long long s_prefix;
    __shared__ int s_need, s_cnt;
    int g = blockIdx.x, tid = threadIdx.x;
    const float* sg = score + (size_t)g * Nin;
    for (int i = tid; i < Nin; i += 256) {
        unsigned u = __float_as_uint(sg[i]);
        u = (u & 0x80000000u) ? ~u : (u | 0x80000000u);
        keys[i] = ((unsigned long long)u << 11) | (unsigned long long)(2047 - i);
    }
    if (tid == 0) { s_need = K; s_prefix = 0ull; s_cnt = 0; }
    __syncthreads();
    for (int shift = 40; shift >= 0; shift -= 8) {
        bins[tid] = 0;
        __syncthreads();
        unsigned long long pref = s_prefix;
        int need = s_need;
        int hi = shift + 8;
        for (int i = tid; i < Nin; i += 256) {
            unsigned long long k = keys[i];
            if ((k >> hi) == pref) atomicAdd(&bins[(int)((k >> shift) & 255)], 1);
        }
        __syncthreads();
        ts[tid] = bins[tid];
        __syncthreads();
        for (int o = 1; o < 256; o <<= 1) {
            int add = (tid + o < 256) ? ts[tid + o] : 0;
            __syncthreads();
            ts[tid] += add;
            __syncthreads();
        }
        int nxt = (tid == 255) ? 0 : ts[tid + 1];
        if (ts[tid] >= need && nxt < need) {
            s_prefix = (pref << 8) | (unsigned long long)tid;
            s_need = need - nxt;
        }
        __syncthreads();
    }
    unsigned long long T = s_prefix;
    for (int i = tid; i < Nin; i += 256) {
        if (keys[i] >= T) {
            int r = atomicAdd(&s_cnt, 1);
            int slot = g * K + r;
            sel[slot]  = g * Nin + i;
            vals[slot] = sg[i];
            if (STAGE == 1) new_id[g * N_ + i] = slot;
        } else if (STAGE == 1) {
            new_id[g * N_ + i] = -1;
        }
    }
}

// ---------------- gated max/mean pooling, PB_ blocks per graph ----------------
template<int STAGE>
__launch_bounds__(256)
__global__ void k_pool(const float* conv, const int* sel, const float* vals, float* part) {
    const int K = (STAGE == 1) ? K1_ : K2_;
    int b = blockIdx.x;
    int g = b & 63, c = b >> 6;
    int wv = threadIdx.x >> 6, lane = threadIdx.x & 63;
    float mx = -3.402823466e38f, sm = 0.f;
    for (int r = c * 4 + wv; r < K; r += PB_ * 4) {
        int slot = g * K + r;
        int row  = sel[slot];
        float val = vals[slot];
        float v = conv[(size_t)row * DIM_ + lane] * val;
        mx = fmaxf(mx, v);
        sm += v;
    }
    __shared__ float rmx[4][64], rsm[4][64];
    rmx[wv][lane] = mx; rsm[wv][lane] = sm;
    __syncthreads();
    if (wv == 0) {
        mx = fmaxf(fmaxf(rmx[0][lane], rmx[1][lane]), fmaxf(rmx[2][lane], rmx[3][lane]));
        sm = rsm[0][lane] + rsm[1][lane] + rsm[2][lane] + rsm[3][lane];
        part[((size_t)(g * PB_ + c) * 2 + 0) * 64 + lane] = mx;
        part[((size_t)(g * PB_ + c) * 2 + 1) * 64 + lane] = sm;
    }
}

// ---------------- combine partials -> x1 (stage1) or hbuf = x1 + x2 (stage2) ----------------
template<int STAGE>
__launch_bounds__(64)
__global__ void k_comb(const float* part, float* x1, float* hbuf) {
    const int K = (STAGE == 1) ? K1_ : K2_;
    int g = blockIdx.x, lane = threadIdx.x;
    float mx = -3.402823466e38f, sm = 0.f;
    for (int c = 0; c < PB_; c++) {
        mx = fmaxf(mx, part[((size_t)(g * PB_ + c) * 2 + 0) * 64 + lane]);
        sm += part[((size_t)(g * PB_ + c) * 2 + 1) * 64 + lane];
    }
    float mean = sm / (float)K;
    if (STAGE == 1) {
        x1[g * 128 + lane]      = mx;
        x1[g * 128 + 64 + lane] = mean;
    } else {
        hbuf[g * 128 + lane]      = x1[g * 128 + lane] + mx;
        hbuf[g * 128 + 64 + lane] = x1[g * 128 + 64 + lane] + mean;
    }
}

// ---------------- MLP head ----------------
__launch_bounds__(64)
__global__ void k_head(const float* hbuf, const float* l1w, const float* l1b,
                       const float* l2w, const float* l2b, float* out) {
    __shared__ float h[128];
    __shared__ float h1[64];
    int g = blockIdx.x, t = threadIdx.x;
    h[t]      = hbuf[g * 128 + t];
    h[t + 64] = hbuf[g * 128 + 64 + t];
    __syncthreads();
    float acc = l1b[t];
#pragma unroll 8
    for (int i = 0; i < 128; i++) acc += h[i] * l1w[i * 64 + t];
    h1[t] = fmaxf(acc, 0.0f);
    __syncthreads();
    if (t < NCLS) {
        float o = l2b[t];
#pragma unroll
        for (int i = 0; i < 64; i++) o += h1[i] * l2w[i * NCLS + t];
        out[g * NCLS + t] = o;
    }
}

extern "C" void kernel_launch(void* const* d_in, const int* in_sizes, int n_in,
                              void* d_out, int out_size, void* d_ws, size_t ws_size,
                              hipStream_t stream) {
    const float* x   = (const float*)d_in[0];
    const int*   ei  = (const int*)d_in[1];
    const int*   src = ei;
    const int*   dst = ei + ETOT;
    const float* W1  = (const float*)d_in[3];
    const float* b1  = (const float*)d_in[4];
    const float* p1  = (const float*)d_in[5];
    const float* W2  = (const float*)d_in[6];
    const float* b2  = (const float*)d_in[7];
    const float* p2  = (const float*)d_in[8];
    const float* l1w = (const float*)d_in[9];
    const float* l1b = (const float*)d_in[10];
    const float* l2w = (const float*)d_in[11];
    const float* l2b = (const float*)d_in[12];
    (void)in_sizes; (void)n_in; (void)out_size; (void)ws_size;

    // workspace layout (~81 MB)
    char* ws = (char*)d_ws;
    size_t off = 0;
    auto alloc = [&](size_t bytes) -> void* {
        void* p = ws + off;
        off = (off + bytes + 255) & ~(size_t)255;
        return p;
    };
    float*        bufA  = (float*)       alloc((size_t)NTOT  * DIM_ * 4); // y1 -> conv1
    float*        bufB  = (float*)       alloc((size_t)N2TOT * DIM_ * 4); // y2 -> conv2
    unsigned int* blist = (unsigned int*)alloc((size_t)B_ * CHUNKS_ * BCAP * 4); // 16.8 MB
    int*          bcnt  = (int*)         alloc((size_t)B_ * CHUNKS_ * 4);
    float*        rsq   = (float*)       alloc((size_t)NTOT * 4);
    float*        coef  = (float*)       alloc((size_t)NTOT * 4);
    float*        score = (float*)       alloc((size_t)NTOT * 4);
    int*          newid = (int*)         alloc((size_t)NTOT * 4);
    int*          sel1  = (int*)         alloc((size_t)N2TOT * 4);
    float*        vals1 = (float*)       alloc((size_t)N2TOT * 4);
    int*          sel2  = (int*)         alloc((size_t)B_ * K2_ * 4);
    float*        vals2 = (float*)       alloc((size_t)B_ * K2_ * 4);
    float*        part  = (float*)       alloc((size_t)B_ * PB_ * 128 * 4);
    float*        x1    = (float*)       alloc((size_t)B_ * 128 * 4);
    float*        hbuf  = (float*)       alloc((size_t)B_ * 128 * 4);

    // ---- stage 1 ----
    k_zero<<<2, 256, 0, stream>>>(bcnt, B_ * CHUNKS_);
    k_bucket<1><<<B_ * SLICES_, 256, 0, stream>>>(src, dst, nullptr, bcnt, blist);
    k_degcoef<1><<<B_ * CHUNKS_, 256, 0, stream>>>(bcnt, blist, nullptr, rsq, coef);
    k_scatagg<1><<<B_ * CHUNKS_, 256, 0, stream>>>(x, bcnt, blist, rsq, coef, nullptr, bufA);
    k_convrow<<<NTOT / 256, 256, 0, stream>>>(bufA, W1, b1, p1, score, NTOT);
    k_select<1><<<B_, 256, 0, stream>>>(score, newid, sel1, vals1);
    k_pool<1><<<B_ * PB_, 256, 0, stream>>>(bufA, sel1, vals1, part);
    k_comb<1><<<B_, 64, 0, stream>>>(part, x1, nullptr);

    // ---- stage 2 ----
    k_zero<<<2, 256, 0, stream>>>(bcnt, B_ * CHUNKS_);
    k_bucket<2><<<B_ * SLICES_, 256, 0, stream>>>(src, dst, newid, bcnt, blist);
    k_degcoef<2><<<B_ * CHUNKS_, 256, 0, stream>>>(bcnt, blist, vals1, rsq, coef);
    k_scatagg<2><<<B_ * CHUNKS_, 256, 0, stream>>>(bufA, bcnt, blist, rsq, coef, sel1, bufB);
    k_convrow<<<(N2TOT + 255) / 256, 256, 0, stream>>>(bufB, W2, b2, p2, score, N2TOT);
    k_select<2><<<B_, 256, 0, stream>>>(score, nullptr, sel2, vals2);
    k_pool<2><<<B_ * PB_, 256, 0, stream>>>(bufB, sel2, vals2, part);
    k_comb<2><<<B_, 64, 0, stream>>>(part, x1, hbuf);

    // ---- head ----
    k_head<<<B_, 64, 0, stream>>>(hbuf, l1w, l1b, l2w, l2b, (float*)d_out);
}

// Round 8
// 1567.815 us; speedup vs baseline: 1.0186x; 1.0186x over previous
//
#include <hip/hip_runtime.h>
#include <hip/hip_bf16.h>
#include <cstdint>
#include <cstddef>

#define B_    64
#define N_    2048
#define E_    32768            // edges per graph
#define DIM_  64
#define K1_   1639
#define K2_   1312
#define NTOT  (B_ * N_)        // 131072
#define ETOT  (B_ * E_)        // 2097152
#define N2TOT (B_ * K1_)       // 104896
#define NCLS  6
#define PB_   8                // pooling blocks per graph
#define CHUNKS_ 16             // dst-chunks per graph
#define BCAP  3072             // bucket capacity (mean 2048, sd ~44 -> +23 sigma)
#define SLICES_ 16             // edge slices per graph in k_bucket
#define SCAP  256              // per-slice per-chunk LDS capacity (mean 128, sd ~11)

// ---------------- zero ints ----------------
__global__ void k_zero(int* a, int n) {
    int i = blockIdx.x * 256 + threadIdx.x;
    if (i < n) a[i] = 0;
}

// ---------------- bucket edges by (graph, dst-chunk); packed (dl<<12)|s_local --------------
// 16 slices per graph; graph = b&63 (XCD affinity g&7); one LDS append pass, coalesced out.
template<int STAGE>
__launch_bounds__(256)
__global__ void k_bucket(const int* src, const int* dst, const int* remap,
                         int* bcnt, unsigned int* blist) {
    const int LSTR = (STAGE == 1) ? 128 : 103;
    __shared__ unsigned int lb[CHUNKS_][SCAP];
    __shared__ int lc[CHUNKS_], lbase[CHUNKS_];
    int b = blockIdx.x;
    int g = b & 63, slice = b >> 6;
    int tid = threadIdx.x;
    if (tid < CHUNKS_) lc[tid] = 0;
    __syncthreads();
    const int ESL = E_ / SLICES_;              // 2048
    const int* sp = src + (size_t)g * E_ + slice * ESL;
    const int* dp = dst + (size_t)g * E_ + slice * ESL;
    int gbase = g * ((STAGE == 1) ? N_ : K1_);
    for (int e = tid * 4; e < ESL; e += 1024) {
        int4 ss = *(const int4*)&sp[e];
        int4 dd = *(const int4*)&dp[e];
#pragma unroll
        for (int t = 0; t < 4; t++) {
            int s = (&ss.x)[t], d = (&dd.x)[t];
            if (STAGE == 2) {
                s = remap[s]; d = remap[d];
                if ((s | d) < 0) continue;
                s -= gbase; d -= gbase;
            } else {
                s &= (N_ - 1); d &= (N_ - 1);
            }
            int ch = d / LSTR;
            int dl = d - ch * LSTR;
            int p = atomicAdd(&lc[ch], 1);
            if (p < SCAP) lb[ch][p] = ((unsigned)dl << 12) | (unsigned)s;
        }
    }
    __syncthreads();
    if (tid < CHUNKS_) lbase[tid] = atomicAdd(&bcnt[g * CHUNKS_ + tid], min(lc[tid], SCAP));
    __syncthreads();
    for (int ch = 0; ch < CHUNKS_; ch++) {
        int n = min(lc[ch], SCAP), base0 = lbase[ch];
        unsigned int* out = blist + (size_t)(g * CHUNKS_ + ch) * BCAP + base0;
        for (int i = tid; i < n; i += 256)
            if (base0 + i < BCAP) out[i] = lb[ch][i];
    }
}

// ---------------- per-bucket degree count -> rsq, coef ----------------
// STAGE1: coef = rsq.  STAGE2: coef = vals * rsq.
template<int STAGE>
__launch_bounds__(256)
__global__ void k_degcoef(const int* bcnt, const unsigned int* blist,
                          const float* vals, float* rsq, float* coef) {
    const int NL   = (STAGE == 1) ? N_ : K1_;
    const int LSTR = (STAGE == 1) ? 128 : 103;
    __shared__ int cnt[128];
    int b = blockIdx.x;
    int g = b & 63, ch = b >> 6;
    int tid = threadIdx.x;
    if (tid < LSTR) cnt[tid] = 0;
    __syncthreads();
    int n = min(bcnt[g * CHUNKS_ + ch], BCAP);
    const unsigned int* bl = blist + (size_t)(g * CHUNKS_ + ch) * BCAP;
    for (int i = tid; i < n; i += 256) atomicAdd(&cnt[bl[i] >> 12], 1);
    __syncthreads();
    int lo = ch * LSTR;
    int nloc = min(LSTR, NL - lo);
    if (tid < nloc) {
        int node = g * NL + lo + tid;
        float rv = rsqrtf((float)(cnt[tid] + 1));
        rsq[node] = rv;
        coef[node] = (STAGE == 2) ? vals[node] * rv : rv;
    }
}

// ---------------- scatter-aggregate into LDS tile (native ds_add_f32) ----------------
// acc[dl][lane] += xrows[row(s)][lane] * coef[s]; then y = (acc + self) * rsq, coalesced.
// STAGE2: row(s) = sel[s] (physical stage-1 row).
// NOTE: atomicAdd is applied DIRECTLY to the __shared__ array so the compiler can prove
// LDS address space and emit ds_add_f32 (a generic-pointer helper lowers to a CAS loop
// -> was the R7 780us pathology).
template<int STAGE>
__launch_bounds__(256)
__global__ void k_scatagg(const float* xrows, const int* bcnt, const unsigned int* blist,
                          const float* rsq, const float* coef, const int* sel, float* y) {
    const int NL   = (STAGE == 1) ? N_ : K1_;
    constexpr int LSTR = (STAGE == 1) ? 128 : 103;
    __shared__ float acc[LSTR * DIM_];
    int b = blockIdx.x;
    int g = b & 63, ch = b >> 6;
    int tid = threadIdx.x, lane = tid & 63, wv = tid >> 6;
    for (int i = tid; i < LSTR * DIM_; i += 256) acc[i] = 0.f;
    __syncthreads();
    int n = min(bcnt[g * CHUNKS_ + ch], BCAP);
    const unsigned int* bl = blist + (size_t)(g * CHUNKS_ + ch) * BCAP;
    int gbase = g * NL;
    for (int base = wv * 64; base < n; base += 256) {
        int nch = min(64, n - base);
        unsigned pk = 0; int rowv = 0; float cv = 0.f;
        if (lane < nch) {
            pk = bl[base + lane];
            int snode = gbase + (int)(pk & 0xFFFu);
            rowv = (STAGE == 2) ? sel[snode] : snode;
            cv = coef[snode];
        }
        int i = 0;
        for (; i + 4 <= nch; i += 4) {
            int   r0 = __shfl(rowv, i),     r1 = __shfl(rowv, i+1),
                  r2 = __shfl(rowv, i+2),   r3 = __shfl(rowv, i+3);
            float c0 = __shfl(cv, i),       c1 = __shfl(cv, i+1),
                  c2 = __shfl(cv, i+2),     c3 = __shfl(cv, i+3);
            int   d0 = __shfl((int)(pk>>12), i),   d1 = __shfl((int)(pk>>12), i+1),
                  d2 = __shfl((int)(pk>>12), i+2), d3 = __shfl((int)(pk>>12), i+3);
            float v0 = xrows[(size_t)r0 * DIM_ + lane] * c0;
            float v1 = xrows[(size_t)r1 * DIM_ + lane] * c1;
            float v2 = xrows[(size_t)r2 * DIM_ + lane] * c2;
            float v3 = xrows[(size_t)r3 * DIM_ + lane] * c3;
            atomicAdd(&acc[d0 * DIM_ + lane], v0);
            atomicAdd(&acc[d1 * DIM_ + lane], v1);
            atomicAdd(&acc[d2 * DIM_ + lane], v2);
            atomicAdd(&acc[d3 * DIM_ + lane], v3);
        }
        for (; i < nch; i++) {
            int   rr = __shfl(rowv, i);
            float cc = __shfl(cv, i);
            int   dd = __shfl((int)(pk>>12), i);
            atomicAdd(&acc[dd * DIM_ + lane], xrows[(size_t)rr * DIM_ + lane] * cc);
        }
    }
    __syncthreads();
    int lo = ch * LSTR;
    int nloc = min(LSTR, NL - lo);
    for (int nl = wv; nl < nloc; nl += 4) {
        int node = gbase + lo + nl;
        int srow = (STAGE == 2) ? sel[node] : node;
        float self = xrows[(size_t)srow * DIM_ + lane] * coef[node];
        y[(size_t)node * DIM_ + lane] = (acc[nl * DIM_ + lane] + self) * rsq[node];
    }
}

// ---------------- fused conv row-matmul + bias + ReLU + score (IN PLACE on y) ---------------
__launch_bounds__(256)
__global__ void k_convrow(float* y, const float* W, const float* bias, const float* pvec,
                          float* score, int rows) {
    __shared__ float Wl[DIM_ * DIM_];
    __shared__ float bl[DIM_], pl[DIM_];
    __shared__ float rpn;
    int tid = threadIdx.x;
    for (int i = tid; i < DIM_ * DIM_; i += 256) Wl[i] = W[i];
    if (tid < DIM_) { bl[tid] = bias[tid]; pl[tid] = pvec[tid]; }
    __syncthreads();
    if (tid == 0) {
        float s = 0.0f;
        for (int i = 0; i < DIM_; i++) s += pl[i] * pl[i];
        rpn = rsqrtf(s);
    }
    __syncthreads();
    int row = blockIdx.x * 256 + tid;
    if (row >= rows) return;
    float r[DIM_];
    float4* yp = (float4*)(y + (size_t)row * DIM_);
#pragma unroll
    for (int v = 0; v < 16; v++) {
        float4 q = yp[v];
        r[4*v] = q.x; r[4*v+1] = q.y; r[4*v+2] = q.z; r[4*v+3] = q.w;
    }
    float dot = 0.0f;
#pragma unroll
    for (int jb = 0; jb < 16; jb++) {
        float4 acc = make_float4(bl[jb*4], bl[jb*4+1], bl[jb*4+2], bl[jb*4+3]);
#pragma unroll
        for (int i = 0; i < DIM_; i++) {
            float4 w4 = *(const float4*)&Wl[i * DIM_ + jb * 4];
            acc.x += r[i] * w4.x; acc.y += r[i] * w4.y;
            acc.z += r[i] * w4.z; acc.w += r[i] * w4.w;
        }
        acc.x = fmaxf(acc.x, 0.f); acc.y = fmaxf(acc.y, 0.f);
        acc.z = fmaxf(acc.z, 0.f); acc.w = fmaxf(acc.w, 0.f);
        dot += acc.x * pl[jb*4] + acc.y * pl[jb*4+1] + acc.z * pl[jb*4+2] + acc.w * pl[jb*4+3];
        yp[jb] = acc;
    }
    score[row] = tanhf(dot * rpn);
}

// ---------------- exact top-K: 6-pass radix select, parallel suffix-sum bin scan ------------
template<int STAGE>
__launch_bounds__(256)
__global__ void k_select(const float* score, int* new_id, int* sel, float* vals) {
    const int Nin = (STAGE == 1) ? N_ : K1_;
    const int K   = (STAGE == 1) ? K1_ : K2_;
    __shared__ unsigned long long keys[N_];
    __shared__ int bins[256], ts[256];
    __shared__ unsigned long long s_prefix;
    __shared__ int s_need, s_cnt;
    int g = blockIdx.x, tid = threadIdx.x;
    const float* sg = score + (size_t)g * Nin;
    for (int i = tid; i < Nin; i += 256) {
        unsigned u = __float_as_uint(sg[i]);
        u = (u & 0x80000000u) ? ~u : (u | 0x80000000u);
        keys[i] = ((unsigned long long)u << 11) | (unsigned long long)(2047 - i);
    }
    if (tid == 0) { s_need = K; s_prefix = 0ull; s_cnt = 0; }
    __syncthreads();
    for (int shift = 40; shift >= 0; shift -= 8) {
        bins[tid] = 0;
        __syncthreads();
        unsigned long long pref = s_prefix;
        int need = s_need;
        int hi = shift + 8;
        for (int i = tid; i < Nin; i += 256) {
            unsigned long long k = keys[i];
            if ((k >> hi) == pref) atomicAdd(&bins[(int)((k >> shift) & 255)], 1);
        }
        __syncthreads();
        ts[tid] = bins[tid];
        __syncthreads();
        for (int o = 1; o < 256; o <<= 1) {
            int add = (tid + o < 256) ? ts[tid + o] : 0;
            __syncthreads();
            ts[tid] += add;
            __syncthreads();
        }
        int nxt = (tid == 255) ? 0 : ts[tid + 1];
        if (ts[tid] >= need && nxt < need) {
            s_prefix = (pref << 8) | (unsigned long long)tid;
            s_need = need - nxt;
        }
        __syncthreads();
    }
    unsigned long long T = s_prefix;
    for (int i = tid; i < Nin; i += 256) {
        if (keys[i] >= T) {
            int r = atomicAdd(&s_cnt, 1);
            int slot = g * K + r;
            sel[slot]  = g * Nin + i;
            vals[slot] = sg[i];
            if (STAGE == 1) new_id[g * N_ + i] = slot;
        } else if (STAGE == 1) {
            new_id[g * N_ + i] = -1;
        }
    }
}

// ---------------- gated max/mean pooling, PB_ blocks per graph ----------------
template<int STAGE>
__launch_bounds__(256)
__global__ void k_pool(const float* conv, const int* sel, const float* vals, float* part) {
    const int K = (STAGE == 1) ? K1_ : K2_;
    int b = blockIdx.x;
    int g = b & 63, c = b >> 6;
    int wv = threadIdx.x >> 6, lane = threadIdx.x & 63;
    float mx = -3.402823466e38f, sm = 0.f;
    for (int r = c * 4 + wv; r < K; r += PB_ * 4) {
        int slot = g * K + r;
        int row  = sel[slot];
        float val = vals[slot];
        float v = conv[(size_t)row * DIM_ + lane] * val;
        mx = fmaxf(mx, v);
        sm += v;
    }
    __shared__ float rmx[4][64], rsm[4][64];
    rmx[wv][lane] = mx; rsm[wv][lane] = sm;
    __syncthreads();
    if (wv == 0) {
        mx = fmaxf(fmaxf(rmx[0][lane], rmx[1][lane]), fmaxf(rmx[2][lane], rmx[3][lane]));
        sm = rsm[0][lane] + rsm[1][lane] + rsm[2][lane] + rsm[3][lane];
        part[((size_t)(g * PB_ + c) * 2 + 0) * 64 + lane] = mx;
        part[((size_t)(g * PB_ + c) * 2 + 1) * 64 + lane] = sm;
    }
}

// ---------------- combine partials -> x1 (stage1) or hbuf = x1 + x2 (stage2) ----------------
template<int STAGE>
__launch_bounds__(64)
__global__ void k_comb(const float* part, float* x1, float* hbuf) {
    const int K = (STAGE == 1) ? K1_ : K2_;
    int g = blockIdx.x, lane = threadIdx.x;
    float mx = -3.402823466e38f, sm = 0.f;
    for (int c = 0; c < PB_; c++) {
        mx = fmaxf(mx, part[((size_t)(g * PB_ + c) * 2 + 0) * 64 + lane]);
        sm += part[((size_t)(g * PB_ + c) * 2 + 1) * 64 + lane];
    }
    float mean = sm / (float)K;
    if (STAGE == 1) {
        x1[g * 128 + lane]      = mx;
        x1[g * 128 + 64 + lane] = mean;
    } else {
        hbuf[g * 128 + lane]      = x1[g * 128 + lane] + mx;
        hbuf[g * 128 + 64 + lane] = x1[g * 128 + 64 + lane] + mean;
    }
}

// ---------------- MLP head ----------------
__launch_bounds__(64)
__global__ void k_head(const float* hbuf, const float* l1w, const float* l1b,
                       const float* l2w, const float* l2b, float* out) {
    __shared__ float h[128];
    __shared__ float h1[64];
    int g = blockIdx.x, t = threadIdx.x;
    h[t]      = hbuf[g * 128 + t];
    h[t + 64] = hbuf[g * 128 + 64 + t];
    __syncthreads();
    float acc = l1b[t];
#pragma unroll 8
    for (int i = 0; i < 128; i++) acc += h[i] * l1w[i * 64 + t];
    h1[t] = fmaxf(acc, 0.0f);
    __syncthreads();
    if (t < NCLS) {
        float o = l2b[t];
#pragma unroll
        for (int i = 0; i < 64; i++) o += h1[i] * l2w[i * NCLS + t];
        out[g * NCLS + t] = o;
    }
}

extern "C" void kernel_launch(void* const* d_in, const int* in_sizes, int n_in,
                              void* d_out, int out_size, void* d_ws, size_t ws_size,
                              hipStream_t stream) {
    const float* x   = (const float*)d_in[0];
    const int*   ei  = (const int*)d_in[1];
    const int*   src = ei;
    const int*   dst = ei + ETOT;
    const float* W1  = (const float*)d_in[3];
    const float* b1  = (const float*)d_in[4];
    const float* p1  = (const float*)d_in[5];
    const float* W2  = (const float*)d_in[6];
    const float* b2  = (const float*)d_in[7];
    const float* p2  = (const float*)d_in[8];
    const float* l1w = (const float*)d_in[9];
    const float* l1b = (const float*)d_in[10];
    const float* l2w = (const float*)d_in[11];
    const float* l2b = (const float*)d_in[12];
    (void)in_sizes; (void)n_in; (void)out_size; (void)ws_size;

    // workspace layout (~77 MB)
    char* ws = (char*)d_ws;
    size_t off = 0;
    auto alloc = [&](size_t bytes) -> void* {
        void* p = ws + off;
        off = (off + bytes + 255) & ~(size_t)255;
        return p;
    };
    float*        bufA  = (float*)       alloc((size_t)NTOT  * DIM_ * 4); // y1 -> conv1
    float*        bufB  = (float*)       alloc((size_t)N2TOT * DIM_ * 4); // y2 -> conv2
    unsigned int* blist = (unsigned int*)alloc((size_t)B_ * CHUNKS_ * BCAP * 4); // 12.6 MB
    int*          bcnt  = (int*)         alloc((size_t)B_ * CHUNKS_ * 4);
    float*        rsq   = (float*)       alloc((size_t)NTOT * 4);
    float*        coef  = (float*)       alloc((size_t)NTOT * 4);
    float*        score = (float*)       alloc((size_t)NTOT * 4);
    int*          newid = (int*)         alloc((size_t)NTOT * 4);
    int*          sel1  = (int*)         alloc((size_t)N2TOT * 4);
    float*        vals1 = (float*)       alloc((size_t)N2TOT * 4);
    int*          sel2  = (int*)         alloc((size_t)B_ * K2_ * 4);
    float*        vals2 = (float*)       alloc((size_t)B_ * K2_ * 4);
    float*        part  = (float*)       alloc((size_t)B_ * PB_ * 128 * 4);
    float*        x1    = (float*)       alloc((size_t)B_ * 128 * 4);
    float*        hbuf  = (float*)       alloc((size_t)B_ * 128 * 4);

    // ---- stage 1 ----
    k_zero<<<4, 256, 0, stream>>>(bcnt, B_ * CHUNKS_);
    k_bucket<1><<<B_ * SLICES_, 256, 0, stream>>>(src, dst, nullptr, bcnt, blist);
    k_degcoef<1><<<B_ * CHUNKS_, 256, 0, stream>>>(bcnt, blist, nullptr, rsq, coef);
    k_scatagg<1><<<B_ * CHUNKS_, 256, 0, stream>>>(x, bcnt, blist, rsq, coef, nullptr, bufA);
    k_convrow<<<NTOT / 256, 256, 0, stream>>>(bufA, W1, b1, p1, score, NTOT);
    k_select<1><<<B_, 256, 0, stream>>>(score, newid, sel1, vals1);
    k_pool<1><<<B_ * PB_, 256, 0, stream>>>(bufA, sel1, vals1, part);
    k_comb<1><<<B_, 64, 0, stream>>>(part, x1, nullptr);

    // ---- stage 2 ----
    k_zero<<<4, 256, 0, stream>>>(bcnt, B_ * CHUNKS_);
    k_bucket<2><<<B_ * SLICES_, 256, 0, stream>>>(src, dst, newid, bcnt, blist);
    k_degcoef<2><<<B_ * CHUNKS_, 256, 0, stream>>>(bcnt, blist, vals1, rsq, coef);
    k_scatagg<2><<<B_ * CHUNKS_, 256, 0, stream>>>(bufA, bcnt, blist, rsq, coef, sel1, bufB);
    k_convrow<<<(N2TOT + 255) / 256, 256, 0, stream>>>(bufB, W2, b2, p2, score, N2TOT);
    k_select<2><<<B_, 256, 0, stream>>>(score, nullptr, sel2, vals2);
    k_pool<2><<<B_ * PB_, 256, 0, stream>>>(bufB, sel2, vals2, part);
    k_comb<2><<<B_, 64, 0, stream>>>(part, x1, hbuf);

    // ---- head ----
    k_head<<<B_, 64, 0, stream>>>(hbuf, l1w, l1b, l2w, l2b, (float*)d_out);
}

// Round 9
// 432.260 us; speedup vs baseline: 3.6945x; 3.6270x over previous
//
#include <hip/hip_runtime.h>
#include <hip/hip_bf16.h>
#include <cstdint>
#include <cstddef>

#define B_    64
#define N_    2048
#define E_    32768            // edges per graph
#define DIM_  64
#define K1_   1639
#define K2_   1312
#define NTOT  (B_ * N_)        // 131072
#define ETOT  (B_ * E_)        // 2097152
#define N2TOT (B_ * K1_)       // 104896
#define NCLS  6
#define PB_   8                // pooling blocks per graph
#define CHUNKS_ 16             // dst-chunks per graph
#define BCAP  3072             // bucket capacity (mean 2048, sd ~45 -> +22 sigma)
#define SLICES_ 16             // edge slices per graph in k_bucket
#define SCAP  256              // per-slice per-chunk LDS capacity (mean 128, sd ~11)

// ---------------- zero ints ----------------
__global__ void k_zero(int* a, int n) {
    int i = blockIdx.x * 256 + threadIdx.x;
    if (i < n) a[i] = 0;
}

// ---------------- bucket edges by (graph, dst-chunk); packed (dl<<12)|s_local --------------
// 16 slices per graph; graph = b&63 (XCD affinity g&7); INT LDS atomics only (proven fast).
template<int STAGE>
__launch_bounds__(256)
__global__ void k_bucket(const int* src, const int* dst, const int* remap,
                         int* bcnt, unsigned int* blist) {
    const int LSTR = (STAGE == 1) ? 128 : 103;
    __shared__ unsigned int lb[CHUNKS_][SCAP];
    __shared__ int lc[CHUNKS_], lbase[CHUNKS_];
    int b = blockIdx.x;
    int g = b & 63, slice = b >> 6;
    int tid = threadIdx.x;
    if (tid < CHUNKS_) lc[tid] = 0;
    __syncthreads();
    const int ESL = E_ / SLICES_;              // 2048
    const int* sp = src + (size_t)g * E_ + slice * ESL;
    const int* dp = dst + (size_t)g * E_ + slice * ESL;
    int gbase = g * ((STAGE == 1) ? N_ : K1_);
    for (int e = tid * 4; e < ESL; e += 1024) {
        int4 ss = *(const int4*)&sp[e];
        int4 dd = *(const int4*)&dp[e];
#pragma unroll
        for (int t = 0; t < 4; t++) {
            int s = (&ss.x)[t], d = (&dd.x)[t];
            if (STAGE == 2) {
                s = remap[s]; d = remap[d];
                if ((s | d) < 0) continue;     // edge touches a dropped node
                s -= gbase; d -= gbase;
            } else {
                s &= (N_ - 1); d &= (N_ - 1);
            }
            int ch = d / LSTR;
            int dl = d - ch * LSTR;
            int p = atomicAdd(&lc[ch], 1);
            if (p < SCAP) lb[ch][p] = ((unsigned)dl << 12) | (unsigned)s;
        }
    }
    __syncthreads();
    if (tid < CHUNKS_) lbase[tid] = atomicAdd(&bcnt[g * CHUNKS_ + tid], min(lc[tid], SCAP));
    __syncthreads();
    for (int ch = 0; ch < CHUNKS_; ch++) {
        int n = min(lc[ch], SCAP), base0 = lbase[ch];
        unsigned int* out = blist + (size_t)(g * CHUNKS_ + ch) * BCAP + base0;
        for (int i = tid; i < n; i += 256)
            if (base0 + i < BCAP) out[i] = lb[ch][i];
    }
}

// ---------------- counting-sort bucket by dst -> compact CSR + ninfo + coef ----------------
// One block per (graph, chunk). INT LDS atomics + 128-wide scan. All global I/O coalesced.
// ninfo[node] = (global_csr_start << 8) | cnt.  STAGE1: coef=rsqrt(cnt+1); STAGE2: *vals.
template<int STAGE>
__launch_bounds__(256)
__global__ void k_sort(const int* bcnt, const unsigned int* blist, const float* vals,
                       unsigned short* csr, int* ninfo, float* coef) {
    const int NL   = (STAGE == 1) ? N_ : K1_;
    const int LSTR = (STAGE == 1) ? 128 : 103;
    __shared__ int cnt[128], st[128], cur[128];
    __shared__ unsigned short sorted[BCAP];
    int b = blockIdx.x;
    int g = b & 63, ch = b >> 6;
    int tid = threadIdx.x;
    if (tid < 128) { cnt[tid] = 0; cur[tid] = 0; }
    __syncthreads();
    int n = min(bcnt[g * CHUNKS_ + ch], BCAP);
    const unsigned int* bl = blist + (size_t)(g * CHUNKS_ + ch) * BCAP;
    for (int i = tid; i < n; i += 256) atomicAdd(&cnt[bl[i] >> 12], 1);
    __syncthreads();
    if (tid < 128) st[tid] = cnt[tid];
    __syncthreads();
    for (int o = 1; o < 128; o <<= 1) {        // inclusive scan over 128 counters
        int add = (tid >= o && tid < 128) ? st[tid - o] : 0;
        __syncthreads();
        if (tid < 128) st[tid] += add;
        __syncthreads();
    }
    for (int i = tid; i < n; i += 256) {       // place into sorted order
        unsigned pk = bl[i];
        int dl = (int)(pk >> 12);
        int p = st[dl] - cnt[dl] + atomicAdd(&cur[dl], 1);
        sorted[p] = (unsigned short)(pk & 0xFFFu);
    }
    __syncthreads();
    int cb = (g * CHUNKS_ + ch) * BCAP;
    for (int i = tid; i < n; i += 256) csr[cb + i] = sorted[i];
    int lo = ch * LSTR;
    int nloc = min(LSTR, NL - lo);
    if (tid < nloc) {
        int node = g * NL + lo + tid;
        int c = cnt[tid];
        int start = cb + st[tid] - c;
        ninfo[node] = (start << 8) | min(c, 255);
        float rv = rsqrtf((float)(c + 1));
        coef[node] = (STAGE == 2) ? vals[node] * rv : rv;
    }
}

// ---------------- gather-aggregate, XCD-swizzled, compact CSR (R6-proven) ----------------
// y[d] = ( sum_{s in in(d)} xrows[row(s)]*ncoef[s] + xrows[row(d)]*selfc ) * rsqrt(cnt+1)
// GATE=false: row(s)=s, selfc=rd.  GATE=true: row(s)=sel[s], selfc=ncoef[d].
template<bool GATE>
__launch_bounds__(256)
__global__ void k_agg(const float* xrows, const int* nodeinfo, const unsigned short* csr,
                      const float* ncoef, const int* sel, float* y) {
    int b = blockIdx.x;
    int xcd = b & 7, r = b >> 3;
    int graph, local;
    if (GATE) {
        graph = xcd * 8 + r / 410;            // ceil(1639/4)=410 blocks/graph
        local = (r % 410) * 4 + (threadIdx.x >> 6);
        if (local >= K1_) return;
    } else {
        graph = xcd * 8 + (r >> 9);           // 512 blocks/graph
        local = (r & 511) * 4 + (threadIdx.x >> 6);
    }
    const int NL = GATE ? K1_ : N_;
    int node = graph * NL + local;
    int lane = threadIdx.x & 63;
    int ni = nodeinfo[node];
    int cnt = ni & 255, base = ni >> 8;
    float rd = rsqrtf((float)(cnt + 1));
    float a0 = 0.f, a1 = 0.f, a2 = 0.f, a3 = 0.f;
    for (int chunk = 0; chunk < cnt; chunk += 64) {
        int nch = min(64, cnt - chunk);
        int sv = 0; float cv = 0.f;
        if (lane < nch) {
            int s = graph * NL + (int)csr[base + chunk + lane];
            sv = GATE ? sel[s] : s;
            cv = ncoef[s];
        }
        int i = 0;
        for (; i + 4 <= nch; i += 4) {
            int   r0 = __shfl(sv, i),   r1 = __shfl(sv, i+1),
                  r2 = __shfl(sv, i+2), r3 = __shfl(sv, i+3);
            float c0 = __shfl(cv, i),   c1 = __shfl(cv, i+1),
                  c2 = __shfl(cv, i+2), c3 = __shfl(cv, i+3);
            a0 += xrows[(size_t)r0 * DIM_ + lane] * c0;
            a1 += xrows[(size_t)r1 * DIM_ + lane] * c1;
            a2 += xrows[(size_t)r2 * DIM_ + lane] * c2;
            a3 += xrows[(size_t)r3 * DIM_ + lane] * c3;
        }
        for (; i < nch; i++) {
            int rr = __shfl(sv, i); float cc = __shfl(cv, i);
            a0 += xrows[(size_t)rr * DIM_ + lane] * cc;
        }
    }
    int snode = GATE ? sel[node] : node;
    float selfc = GATE ? ncoef[node] : rd;
    a0 += xrows[(size_t)snode * DIM_ + lane] * selfc;
    y[(size_t)node * DIM_ + lane] = ((a0 + a1) + (a2 + a3)) * rd;
}

// ---------------- fused conv row-matmul + bias + ReLU + score (IN PLACE on y) ---------------
__launch_bounds__(256)
__global__ void k_convrow(float* y, const float* W, const float* bias, const float* pvec,
                          float* score, int rows) {
    __shared__ float Wl[DIM_ * DIM_];
    __shared__ float bl[DIM_], pl[DIM_];
    __shared__ float rpn;
    int tid = threadIdx.x;
    for (int i = tid; i < DIM_ * DIM_; i += 256) Wl[i] = W[i];
    if (tid < DIM_) { bl[tid] = bias[tid]; pl[tid] = pvec[tid]; }
    __syncthreads();
    if (tid == 0) {
        float s = 0.0f;
        for (int i = 0; i < DIM_; i++) s += pl[i] * pl[i];
        rpn = rsqrtf(s);
    }
    __syncthreads();
    int row = blockIdx.x * 256 + tid;
    if (row >= rows) return;
    float r[DIM_];
    float4* yp = (float4*)(y + (size_t)row * DIM_);
#pragma unroll
    for (int v = 0; v < 16; v++) {
        float4 q = yp[v];
        r[4*v] = q.x; r[4*v+1] = q.y; r[4*v+2] = q.z; r[4*v+3] = q.w;
    }
    float dot = 0.0f;
#pragma unroll
    for (int jb = 0; jb < 16; jb++) {
        float4 acc = make_float4(bl[jb*4], bl[jb*4+1], bl[jb*4+2], bl[jb*4+3]);
#pragma unroll
        for (int i = 0; i < DIM_; i++) {
            float4 w4 = *(const float4*)&Wl[i * DIM_ + jb * 4];
            acc.x += r[i] * w4.x; acc.y += r[i] * w4.y;
            acc.z += r[i] * w4.z; acc.w += r[i] * w4.w;
        }
        acc.x = fmaxf(acc.x, 0.f); acc.y = fmaxf(acc.y, 0.f);
        acc.z = fmaxf(acc.z, 0.f); acc.w = fmaxf(acc.w, 0.f);
        dot += acc.x * pl[jb*4] + acc.y * pl[jb*4+1] + acc.z * pl[jb*4+2] + acc.w * pl[jb*4+3];
        yp[jb] = acc;
    }
    score[row] = tanhf(dot * rpn);
}

// ---------------- exact top-K: 6-pass radix select, parallel suffix-sum bin scan ------------
template<int STAGE>
__launch_bounds__(256)
__global__ void k_select(const float* score, int* new_id, int* sel, float* vals) {
    const int Nin = (STAGE == 1) ? N_ : K1_;
    const int K   = (STAGE == 1) ? K1_ : K2_;
    __shared__ unsigned long long keys[N_];
    __shared__ int bins[256], ts[256];
    __shared__ unsigned long long s_prefix;
    __shared__ int s_need, s_cnt;
    int g = blockIdx.x, tid = threadIdx.x;
    const float* sg = score + (size_t)g * Nin;
    for (int i = tid; i < Nin; i += 256) {
        unsigned u = __float_as_uint(sg[i]);
        u = (u & 0x80000000u) ? ~u : (u | 0x80000000u);
        keys[i] = ((unsigned long long)u << 11) | (unsigned long long)(2047 - i);
    }
    if (tid == 0) { s_need = K; s_prefix = 0ull; s_cnt = 0; }
    __syncthreads();
    for (int shift = 40; shift >= 0; shift -= 8) {
        bins[tid] = 0;
        __syncthreads();
        unsigned long long pref = s_prefix;
        int need = s_need;
        int hi = shift + 8;
        for (int i = tid; i < Nin; i += 256) {
            unsigned long long k = keys[i];
            if ((k >> hi) == pref) atomicAdd(&bins[(int)((k >> shift) & 255)], 1);
        }
        __syncthreads();
        ts[tid] = bins[tid];
        __syncthreads();
        for (int o = 1; o < 256; o <<= 1) {
            int add = (tid + o < 256) ? ts[tid + o] : 0;
            __syncthreads();
            ts[tid] += add;
            __syncthreads();
        }
        int nxt = (tid == 255) ? 0 : ts[tid + 1];
        if (ts[tid] >= need && nxt < need) {
            s_prefix = (pref << 8) | (unsigned long long)tid;
            s_need = need - nxt;
        }
        __syncthreads();
    }
    unsigned long long T = s_prefix;
    for (int i = tid; i < Nin; i += 256) {
        if (keys[i] >= T) {
            int r = atomicAdd(&s_cnt, 1);
            int slot = g * K + r;
            sel[slot]  = g * Nin + i;
            vals[slot] = sg[i];
            if (STAGE == 1) new_id[g * N_ + i] = slot;
        } else if (STAGE == 1) {
            new_id[g * N_ + i] = -1;
        }
    }
}

// ---------------- gated max/mean pooling, PB_ blocks per graph ----------------
template<int STAGE>
__launch_bounds__(256)
__global__ void k_pool(const float* conv, const int* sel, const float* vals, float* part) {
    const int K = (STAGE == 1) ? K1_ : K2_;
    int b = blockIdx.x;
    int g = b & 63, c = b >> 6;
    int wv = threadIdx.x >> 6, lane = threadIdx.x & 63;
    float mx = -3.402823466e38f, sm = 0.f;
    for (int r = c * 4 + wv; r < K; r += PB_ * 4) {
        int slot = g * K + r;
        int row  = sel[slot];
        float val = vals[slot];
        float v = conv[(size_t)row * DIM_ + lane] * val;
        mx = fmaxf(mx, v);
        sm += v;
    }
    __shared__ float rmx[4][64], rsm[4][64];
    rmx[wv][lane] = mx; rsm[wv][lane] = sm;
    __syncthreads();
    if (wv == 0) {
        mx = fmaxf(fmaxf(rmx[0][lane], rmx[1][lane]), fmaxf(rmx[2][lane], rmx[3][lane]));
        sm = rsm[0][lane] + rsm[1][lane] + rsm[2][lane] + rsm[3][lane];
        part[((size_t)(g * PB_ + c) * 2 + 0) * 64 + lane] = mx;
        part[((size_t)(g * PB_ + c) * 2 + 1) * 64 + lane] = sm;
    }
}

// ---------------- combine partials -> x1 (stage1) or hbuf = x1 + x2 (stage2) ----------------
template<int STAGE>
__launch_bounds__(64)
__global__ void k_comb(const float* part, float* x1, float* hbuf) {
    const int K = (STAGE == 1) ? K1_ : K2_;
    int g = blockIdx.x, lane = threadIdx.x;
    float mx = -3.402823466e38f, sm = 0.f;
    for (int c = 0; c < PB_; c++) {
        mx = fmaxf(mx, part[((size_t)(g * PB_ + c) * 2 + 0) * 64 + lane]);
        sm += part[((size_t)(g * PB_ + c) * 2 + 1) * 64 + lane];
    }
    float mean = sm / (float)K;
    if (STAGE == 1) {
        x1[g * 128 + lane]      = mx;
        x1[g * 128 + 64 + lane] = mean;
    } else {
        hbuf[g * 128 + lane]      = x1[g * 128 + lane] + mx;
        hbuf[g * 128 + 64 + lane] = x1[g * 128 + 64 + lane] + mean;
    }
}

// ---------------- MLP head ----------------
__launch_bounds__(64)
__global__ void k_head(const float* hbuf, const float* l1w, const float* l1b,
                       const float* l2w, const float* l2b, float* out) {
    __shared__ float h[128];
    __shared__ float h1[64];
    int g = blockIdx.x, t = threadIdx.x;
    h[t]      = hbuf[g * 128 + t];
    h[t + 64] = hbuf[g * 128 + 64 + t];
    __syncthreads();
    float acc = l1b[t];
#pragma unroll 8
    for (int i = 0; i < 128; i++) acc += h[i] * l1w[i * 64 + t];
    h1[t] = fmaxf(acc, 0.0f);
    __syncthreads();
    if (t < NCLS) {
        float o = l2b[t];
#pragma unroll
        for (int i = 0; i < 64; i++) o += h1[i] * l2w[i * NCLS + t];
        out[g * NCLS + t] = o;
    }
}

extern "C" void kernel_launch(void* const* d_in, const int* in_sizes, int n_in,
                              void* d_out, int out_size, void* d_ws, size_t ws_size,
                              hipStream_t stream) {
    const float* x   = (const float*)d_in[0];
    const int*   ei  = (const int*)d_in[1];
    const int*   src = ei;
    const int*   dst = ei + ETOT;
    const float* W1  = (const float*)d_in[3];
    const float* b1  = (const float*)d_in[4];
    const float* p1  = (const float*)d_in[5];
    const float* W2  = (const float*)d_in[6];
    const float* b2  = (const float*)d_in[7];
    const float* p2  = (const float*)d_in[8];
    const float* l1w = (const float*)d_in[9];
    const float* l1b = (const float*)d_in[10];
    const float* l2w = (const float*)d_in[11];
    const float* l2b = (const float*)d_in[12];
    (void)in_sizes; (void)n_in; (void)out_size; (void)ws_size;

    // workspace layout (~84 MB)
    char* ws = (char*)d_ws;
    size_t off = 0;
    auto alloc = [&](size_t bytes) -> void* {
        void* p = ws + off;
        off = (off + bytes + 255) & ~(size_t)255;
        return p;
    };
    float*          bufA  = (float*)         alloc((size_t)NTOT  * DIM_ * 4); // y1 -> conv1
    float*          bufB  = (float*)         alloc((size_t)N2TOT * DIM_ * 4); // y2 -> conv2
    unsigned int*   blist = (unsigned int*)  alloc((size_t)B_ * CHUNKS_ * BCAP * 4); // 12.6 MB
    unsigned short* csr   = (unsigned short*)alloc((size_t)B_ * CHUNKS_ * BCAP * 2); // 6.3 MB
    int*            bcnt  = (int*)           alloc((size_t)B_ * CHUNKS_ * 4);
    int*            ninfo = (int*)           alloc((size_t)NTOT * 4);
    float*          coef  = (float*)         alloc((size_t)NTOT * 4);
    float*          score = (float*)         alloc((size_t)NTOT * 4);
    int*            newid = (int*)           alloc((size_t)NTOT * 4);
    int*            sel1  = (int*)           alloc((size_t)N2TOT * 4);
    float*          vals1 = (float*)         alloc((size_t)N2TOT * 4);
    int*            sel2  = (int*)           alloc((size_t)B_ * K2_ * 4);
    float*          vals2 = (float*)         alloc((size_t)B_ * K2_ * 4);
    float*          part  = (float*)         alloc((size_t)B_ * PB_ * 128 * 4);
    float*          x1    = (float*)         alloc((size_t)B_ * 128 * 4);
    float*          hbuf  = (float*)         alloc((size_t)B_ * 128 * 4);

    // ---- stage 1 ----
    k_zero<<<4, 256, 0, stream>>>(bcnt, B_ * CHUNKS_);
    k_bucket<1><<<B_ * SLICES_, 256, 0, stream>>>(src, dst, nullptr, bcnt, blist);
    k_sort<1><<<B_ * CHUNKS_, 256, 0, stream>>>(bcnt, blist, nullptr, csr, ninfo, coef);
    k_agg<false><<<NTOT / 4, 256, 0, stream>>>(x, ninfo, csr, coef, nullptr, bufA);
    k_convrow<<<NTOT / 256, 256, 0, stream>>>(bufA, W1, b1, p1, score, NTOT);
    k_select<1><<<B_, 256, 0, stream>>>(score, newid, sel1, vals1);
    k_pool<1><<<B_ * PB_, 256, 0, stream>>>(bufA, sel1, vals1, part);
    k_comb<1><<<B_, 64, 0, stream>>>(part, x1, nullptr);

    // ---- stage 2 ----
    k_zero<<<4, 256, 0, stream>>>(bcnt, B_ * CHUNKS_);
    k_bucket<2><<<B_ * SLICES_, 256, 0, stream>>>(src, dst, newid, bcnt, blist);
    k_sort<2><<<B_ * CHUNKS_, 256, 0, stream>>>(bcnt, blist, vals1, csr, ninfo, coef);
    k_agg<true><<<410 * B_, 256, 0, stream>>>(bufA, ninfo, csr, coef, sel1, bufB);
    k_convrow<<<(N2TOT + 255) / 256, 256, 0, stream>>>(bufB, W2, b2, p2, score, N2TOT);
    k_select<2><<<B_, 256, 0, stream>>>(score, nullptr, sel2, vals2);
    k_pool<2><<<B_ * PB_, 256, 0, stream>>>(bufB, sel2, vals2, part);
    k_comb<2><<<B_, 64, 0, stream>>>(part, x1, hbuf);

    // ---- head ----
    k_head<<<B_, 64, 0, stream>>>(hbuf, l1w, l1b, l2w, l2b, (float*)d_out);
}

// Round 10
// 423.513 us; speedup vs baseline: 3.7708x; 1.0207x over previous
//
#include <hip/hip_runtime.h>
#include <hip/hip_bf16.h>
#include <cstdint>
#include <cstddef>

#define B_    64
#define N_    2048
#define E_    32768            // edges per graph
#define DIM_  64
#define K1_   1639
#define K2_   1312
#define NTOT  (B_ * N_)        // 131072
#define ETOT  (B_ * E_)        // 2097152
#define N2TOT (B_ * K1_)       // 104896
#define NCLS  6
#define PB_   8                // pooling blocks per graph
#define CHUNKS_ 16             // dst-chunks per graph
#define BCAP  3072             // bucket capacity (mean 2048, sd ~45 -> +22 sigma)
#define SLICES_ 16             // edge slices per graph in k_bucket
#define SCAP  256              // per-slice per-chunk LDS capacity (mean 128, sd ~11)

// ---------------- zero ints ----------------
__global__ void k_zero(int* a, int n) {
    int i = blockIdx.x * 256 + threadIdx.x;
    if (i < n) a[i] = 0;
}

// ---------------- bucket edges by (graph, dst-chunk); packed (dl<<12)|s_local --------------
template<int STAGE>
__launch_bounds__(256)
__global__ void k_bucket(const int* src, const int* dst, const int* remap,
                         int* bcnt, unsigned int* blist) {
    const int LSTR = (STAGE == 1) ? 128 : 103;
    __shared__ unsigned int lb[CHUNKS_][SCAP];
    __shared__ int lc[CHUNKS_], lbase[CHUNKS_];
    int b = blockIdx.x;
    int g = b & 63, slice = b >> 6;
    int tid = threadIdx.x;
    if (tid < CHUNKS_) lc[tid] = 0;
    __syncthreads();
    const int ESL = E_ / SLICES_;              // 2048
    const int* sp = src + (size_t)g * E_ + slice * ESL;
    const int* dp = dst + (size_t)g * E_ + slice * ESL;
    int gbase = g * ((STAGE == 1) ? N_ : K1_);
    for (int e = tid * 4; e < ESL; e += 1024) {
        int4 ss = *(const int4*)&sp[e];
        int4 dd = *(const int4*)&dp[e];
#pragma unroll
        for (int t = 0; t < 4; t++) {
            int s = (&ss.x)[t], d = (&dd.x)[t];
            if (STAGE == 2) {
                s = remap[s]; d = remap[d];
                if ((s | d) < 0) continue;     // edge touches a dropped node
                s -= gbase; d -= gbase;
            } else {
                s &= (N_ - 1); d &= (N_ - 1);
            }
            int ch = d / LSTR;
            int dl = d - ch * LSTR;
            int p = atomicAdd(&lc[ch], 1);
            if (p < SCAP) lb[ch][p] = ((unsigned)dl << 12) | (unsigned)s;
        }
    }
    __syncthreads();
    if (tid < CHUNKS_) lbase[tid] = atomicAdd(&bcnt[g * CHUNKS_ + tid], min(lc[tid], SCAP));
    __syncthreads();
    for (int ch = 0; ch < CHUNKS_; ch++) {
        int n = min(lc[ch], SCAP), base0 = lbase[ch];
        unsigned int* out = blist + (size_t)(g * CHUNKS_ + ch) * BCAP + base0;
        for (int i = tid; i < n; i += 256)
            if (base0 + i < BCAP) out[i] = lb[ch][i];
    }
}

// ---------------- counting-sort bucket by dst -> compact CSR + ninfo + coef ----------------
template<int STAGE>
__launch_bounds__(256)
__global__ void k_sort(const int* bcnt, const unsigned int* blist, const float* vals,
                       unsigned short* csr, int* ninfo, float* coef) {
    const int NL   = (STAGE == 1) ? N_ : K1_;
    const int LSTR = (STAGE == 1) ? 128 : 103;
    __shared__ int cnt[128], st[128], cur[128];
    __shared__ unsigned short sorted[BCAP];
    int b = blockIdx.x;
    int g = b & 63, ch = b >> 6;
    int tid = threadIdx.x;
    if (tid < 128) { cnt[tid] = 0; cur[tid] = 0; }
    __syncthreads();
    int n = min(bcnt[g * CHUNKS_ + ch], BCAP);
    const unsigned int* bl = blist + (size_t)(g * CHUNKS_ + ch) * BCAP;
    for (int i = tid; i < n; i += 256) atomicAdd(&cnt[bl[i] >> 12], 1);
    __syncthreads();
    if (tid < 128) st[tid] = cnt[tid];
    __syncthreads();
    for (int o = 1; o < 128; o <<= 1) {        // inclusive scan over 128 counters
        int add = (tid >= o && tid < 128) ? st[tid - o] : 0;
        __syncthreads();
        if (tid < 128) st[tid] += add;
        __syncthreads();
    }
    for (int i = tid; i < n; i += 256) {       // place into sorted order
        unsigned pk = bl[i];
        int dl = (int)(pk >> 12);
        int p = st[dl] - cnt[dl] + atomicAdd(&cur[dl], 1);
        sorted[p] = (unsigned short)(pk & 0xFFFu);
    }
    __syncthreads();
    int cb = (g * CHUNKS_ + ch) * BCAP;
    for (int i = tid; i < n; i += 256) csr[cb + i] = sorted[i];
    int lo = ch * LSTR;
    int nloc = min(LSTR, NL - lo);
    if (tid < nloc) {
        int node = g * NL + lo + tid;
        int c = cnt[tid];
        int start = cb + st[tid] - c;
        ninfo[node] = (start << 8) | min(c, 255);
        float rv = rsqrtf((float)(c + 1));
        coef[node] = (STAGE == 2) ? vals[node] * rv : rv;
    }
}

// ---------------- gather-aggregate, float2 edge-pairing ----------------
// Wave per node. Lanes 0-31 process edge i, lanes 32-63 edge i+1; each lane covers 2
// features (float2). Halves combined at the end via shfl(lane^32).
template<bool GATE>
__launch_bounds__(256)
__global__ void k_agg(const float* xrows, const int* nodeinfo, const unsigned short* csr,
                      const float* ncoef, const int* sel, float* y) {
    int b = blockIdx.x;
    int xcd = b & 7, r = b >> 3;
    int graph, local;
    if (GATE) {
        graph = xcd * 8 + r / 410;            // ceil(1639/4)=410 blocks/graph
        local = (r % 410) * 4 + (threadIdx.x >> 6);
        if (local >= K1_) return;
    } else {
        graph = xcd * 8 + (r >> 9);           // 512 blocks/graph
        local = (r & 511) * 4 + (threadIdx.x >> 6);
    }
    const int NL = GATE ? K1_ : N_;
    int node = graph * NL + local;
    int lane = threadIdx.x & 63;
    int half = lane >> 5;                      // which edge of the pair
    int fpos = lane & 31;                      // float2 slot within the row
    int ni = nodeinfo[node];
    int cnt = ni & 255, base = ni >> 8;
    float rd = rsqrtf((float)(cnt + 1));
    const float2* x2 = (const float2*)xrows;
    float ax = 0.f, ay = 0.f, bx = 0.f, by = 0.f;
    for (int chunk = 0; chunk < cnt; chunk += 64) {
        int nch = min(64, cnt - chunk);
        int sv = 0; float cv = 0.f;
        if (lane < nch) {
            int s = graph * NL + (int)csr[base + chunk + lane];
            sv = GATE ? sel[s] : s;
            cv = ncoef[s];
        }
        int i = 0;
        for (; i + 4 <= nch; i += 4) {         // 4 edges per iteration (2 pairs)
            int   s0 = __shfl(sv, i + half),  s1 = __shfl(sv, i + 2 + half);
            float c0 = __shfl(cv, i + half),  c1 = __shfl(cv, i + 2 + half);
            float2 v0 = x2[(size_t)s0 * 32 + fpos];
            float2 v1 = x2[(size_t)s1 * 32 + fpos];
            ax += v0.x * c0; ay += v0.y * c0;
            bx += v1.x * c1; by += v1.y * c1;
        }
        for (; i < nch; i += 2) {              // tail pair (possibly half-empty)
            int idx = i + half;
            int   s0 = __shfl(sv, idx & 63);
            float c0 = __shfl(cv, idx & 63);
            if (idx >= nch) c0 = 0.f;          // sv from a zeroed lane is row 0: safe, c0=0
            float2 v0 = x2[(size_t)s0 * 32 + fpos];
            ax += v0.x * c0; ay += v0.y * c0;
        }
    }
    float sx = ax + bx, sy = ay + by;
    sx += __shfl(sx, lane ^ 32);               // combine the two halves
    sy += __shfl(sy, lane ^ 32);
    if (half == 0) {
        int snode = GATE ? sel[node] : node;
        float selfc = GATE ? ncoef[node] : rd;
        float2 sv2 = x2[(size_t)snode * 32 + fpos];
        float2 o;
        o.x = (sx + sv2.x * selfc) * rd;
        o.y = (sy + sv2.y * selfc) * rd;
        ((float2*)y)[(size_t)node * 32 + fpos] = o;
    }
}

// ---------------- fused conv row-matmul + bias + ReLU + score (IN PLACE on y) ---------------
// All 16 output quads kept in registers; stores issued back-to-back at the end so each
// 128B line is fully written within a few instructions (fixes 4.4x HBM write amplification).
__launch_bounds__(256)
__global__ void k_convrow(float* y, const float* W, const float* bias, const float* pvec,
                          float* score, int rows) {
    __shared__ float Wl[DIM_ * DIM_];
    __shared__ float bl[DIM_], pl[DIM_];
    __shared__ float rpn;
    int tid = threadIdx.x;
    for (int i = tid; i < DIM_ * DIM_; i += 256) Wl[i] = W[i];
    if (tid < DIM_) { bl[tid] = bias[tid]; pl[tid] = pvec[tid]; }
    __syncthreads();
    if (tid == 0) {
        float s = 0.0f;
        for (int i = 0; i < DIM_; i++) s += pl[i] * pl[i];
        rpn = rsqrtf(s);
    }
    __syncthreads();
    int row = blockIdx.x * 256 + tid;
    if (row >= rows) return;
    float r[DIM_];
    float4* yp = (float4*)(y + (size_t)row * DIM_);
#pragma unroll
    for (int v = 0; v < 16; v++) {
        float4 q = yp[v];
        r[4*v] = q.x; r[4*v+1] = q.y; r[4*v+2] = q.z; r[4*v+3] = q.w;
    }
    float4 a[16];
    float dot = 0.0f;
#pragma unroll
    for (int jb = 0; jb < 16; jb++) {
        float4 acc = make_float4(bl[jb*4], bl[jb*4+1], bl[jb*4+2], bl[jb*4+3]);
#pragma unroll
        for (int i = 0; i < DIM_; i++) {
            float4 w4 = *(const float4*)&Wl[i * DIM_ + jb * 4];
            acc.x += r[i] * w4.x; acc.y += r[i] * w4.y;
            acc.z += r[i] * w4.z; acc.w += r[i] * w4.w;
        }
        acc.x = fmaxf(acc.x, 0.f); acc.y = fmaxf(acc.y, 0.f);
        acc.z = fmaxf(acc.z, 0.f); acc.w = fmaxf(acc.w, 0.f);
        dot += acc.x * pl[jb*4] + acc.y * pl[jb*4+1] + acc.z * pl[jb*4+2] + acc.w * pl[jb*4+3];
        a[jb] = acc;
    }
#pragma unroll
    for (int jb = 0; jb < 16; jb++) yp[jb] = a[jb];
    score[row] = tanhf(dot * rpn);
}

// ---------------- exact top-K: 6-pass radix select, parallel suffix-sum bin scan ------------
template<int STAGE>
__launch_bounds__(256)
__global__ void k_select(const float* score, int* new_id, int* sel, float* vals) {
    const int Nin = (STAGE == 1) ? N_ : K1_;
    const int K   = (STAGE == 1) ? K1_ : K2_;
    __shared__ unsigned long long keys[N_];
    __shared__ int bins[256], ts[256];
    __shared__ unsigned long long s_prefix;
    __shared__ int s_need, s_cnt;
    int g = blockIdx.x, tid = threadIdx.x;
    const float* sg = score + (size_t)g * Nin;
    for (int i = tid; i < Nin; i += 256) {
        unsigned u = __float_as_uint(sg[i]);
        u = (u & 0x80000000u) ? ~u : (u | 0x80000000u);
        keys[i] = ((unsigned long long)u << 11) | (unsigned long long)(2047 - i);
    }
    if (tid == 0) { s_need = K; s_prefix = 0ull; s_cnt = 0; }
    __syncthreads();
    for (int shift = 40; shift >= 0; shift -= 8) {
        bins[tid] = 0;
        __syncthreads();
        unsigned long long pref = s_prefix;
        int need = s_need;
        int hi = shift + 8;
        for (int i = tid; i < Nin; i += 256) {
            unsigned long long k = keys[i];
            if ((k >> hi) == pref) atomicAdd(&bins[(int)((k >> shift) & 255)], 1);
        }
        __syncthreads();
        ts[tid] = bins[tid];
        __syncthreads();
        for (int o = 1; o < 256; o <<= 1) {
            int add = (tid + o < 256) ? ts[tid + o] : 0;
            __syncthreads();
            ts[tid] += add;
            __syncthreads();
        }
        int nxt = (tid == 255) ? 0 : ts[tid + 1];
        if (ts[tid] >= need && nxt < need) {
            s_prefix = (pref << 8) | (unsigned long long)tid;
            s_need = need - nxt;
        }
        __syncthreads();
    }
    unsigned long long T = s_prefix;
    for (int i = tid; i < Nin; i += 256) {
        if (keys[i] >= T) {
            int r = atomicAdd(&s_cnt, 1);
            int slot = g * K + r;
            sel[slot]  = g * Nin + i;
            vals[slot] = sg[i];
            if (STAGE == 1) new_id[g * N_ + i] = slot;
        } else if (STAGE == 1) {
            new_id[g * N_ + i] = -1;
        }
    }
}

// ---------------- gated max/mean pooling, PB_ blocks per graph ----------------
template<int STAGE>
__launch_bounds__(256)
__global__ void k_pool(const float* conv, const int* sel, const float* vals, float* part) {
    const int K = (STAGE == 1) ? K1_ : K2_;
    int b = blockIdx.x;
    int g = b & 63, c = b >> 6;
    int wv = threadIdx.x >> 6, lane = threadIdx.x & 63;
    float mx = -3.402823466e38f, sm = 0.f;
    for (int r = c * 4 + wv; r < K; r += PB_ * 4) {
        int slot = g * K + r;
        int row  = sel[slot];
        float val = vals[slot];
        float v = conv[(size_t)row * DIM_ + lane] * val;
        mx = fmaxf(mx, v);
        sm += v;
    }
    __shared__ float rmx[4][64], rsm[4][64];
    rmx[wv][lane] = mx; rsm[wv][lane] = sm;
    __syncthreads();
    if (wv == 0) {
        mx = fmaxf(fmaxf(rmx[0][lane], rmx[1][lane]), fmaxf(rmx[2][lane], rmx[3][lane]));
        sm = rsm[0][lane] + rsm[1][lane] + rsm[2][lane] + rsm[3][lane];
        part[((size_t)(g * PB_ + c) * 2 + 0) * 64 + lane] = mx;
        part[((size_t)(g * PB_ + c) * 2 + 1) * 64 + lane] = sm;
    }
}

// ---------------- MLP head (fused partial-combine for both stages) ----------------
__launch_bounds__(64)
__global__ void k_head(const float* part1, const float* part2,
                       const float* l1w, const float* l1b,
                       const float* l2w, const float* l2b, float* out) {
    __shared__ float h[128];
    __shared__ float h1[64];
    int g = blockIdx.x, t = threadIdx.x;
    float mx1 = -3.402823466e38f, sm1 = 0.f, mx2 = -3.402823466e38f, sm2 = 0.f;
#pragma unroll
    for (int c = 0; c < PB_; c++) {
        mx1 = fmaxf(mx1, part1[((size_t)(g * PB_ + c) * 2 + 0) * 64 + t]);
        sm1 += part1[((size_t)(g * PB_ + c) * 2 + 1) * 64 + t];
        mx2 = fmaxf(mx2, part2[((size_t)(g * PB_ + c) * 2 + 0) * 64 + t]);
        sm2 += part2[((size_t)(g * PB_ + c) * 2 + 1) * 64 + t];
    }
    h[t]      = mx1 + mx2;
    h[t + 64] = sm1 / (float)K1_ + sm2 / (float)K2_;
    __syncthreads();
    float acc = l1b[t];
#pragma unroll 8
    for (int i = 0; i < 128; i++) acc += h[i] * l1w[i * 64 + t];
    h1[t] = fmaxf(acc, 0.0f);
    __syncthreads();
    if (t < NCLS) {
        float o = l2b[t];
#pragma unroll
        for (int i = 0; i < 64; i++) o += h1[i] * l2w[i * NCLS + t];
        out[g * NCLS + t] = o;
    }
}

extern "C" void kernel_launch(void* const* d_in, const int* in_sizes, int n_in,
                              void* d_out, int out_size, void* d_ws, size_t ws_size,
                              hipStream_t stream) {
    const float* x   = (const float*)d_in[0];
    const int*   ei  = (const int*)d_in[1];
    const int*   src = ei;
    const int*   dst = ei + ETOT;
    const float* W1  = (const float*)d_in[3];
    const float* b1  = (const float*)d_in[4];
    const float* p1  = (const float*)d_in[5];
    const float* W2  = (const float*)d_in[6];
    const float* b2  = (const float*)d_in[7];
    const float* p2  = (const float*)d_in[8];
    const float* l1w = (const float*)d_in[9];
    const float* l1b = (const float*)d_in[10];
    const float* l2w = (const float*)d_in[11];
    const float* l2b = (const float*)d_in[12];
    (void)in_sizes; (void)n_in; (void)out_size; (void)ws_size;

    // workspace layout (~84 MB)
    char* ws = (char*)d_ws;
    size_t off = 0;
    auto alloc = [&](size_t bytes) -> void* {
        void* p = ws + off;
        off = (off + bytes + 255) & ~(size_t)255;
        return p;
    };
    float*          bufA  = (float*)         alloc((size_t)NTOT  * DIM_ * 4); // y1 -> conv1
    float*          bufB  = (float*)         alloc((size_t)N2TOT * DIM_ * 4); // y2 -> conv2
    unsigned int*   blist = (unsigned int*)  alloc((size_t)B_ * CHUNKS_ * BCAP * 4); // 12.6 MB
    unsigned short* csr   = (unsigned short*)alloc((size_t)B_ * CHUNKS_ * BCAP * 2); // 6.3 MB
    int*            bcnt  = (int*)           alloc((size_t)B_ * CHUNKS_ * 4);
    int*            ninfo = (int*)           alloc((size_t)NTOT * 4);
    float*          coef  = (float*)         alloc((size_t)NTOT * 4);
    float*          score = (float*)         alloc((size_t)NTOT * 4);
    int*            newid = (int*)           alloc((size_t)NTOT * 4);
    int*            sel1  = (int*)           alloc((size_t)N2TOT * 4);
    float*          vals1 = (float*)         alloc((size_t)N2TOT * 4);
    int*            sel2  = (int*)           alloc((size_t)B_ * K2_ * 4);
    float*          vals2 = (float*)         alloc((size_t)B_ * K2_ * 4);
    float*          part1 = (float*)         alloc((size_t)B_ * PB_ * 128 * 4);
    float*          part2 = (float*)         alloc((size_t)B_ * PB_ * 128 * 4);

    // ---- stage 1 ----
    k_zero<<<4, 256, 0, stream>>>(bcnt, B_ * CHUNKS_);
    k_bucket<1><<<B_ * SLICES_, 256, 0, stream>>>(src, dst, nullptr, bcnt, blist);
    k_sort<1><<<B_ * CHUNKS_, 256, 0, stream>>>(bcnt, blist, nullptr, csr, ninfo, coef);
    k_agg<false><<<NTOT / 4, 256, 0, stream>>>(x, ninfo, csr, coef, nullptr, bufA);
    k_convrow<<<NTOT / 256, 256, 0, stream>>>(bufA, W1, b1, p1, score, NTOT);
    k_select<1><<<B_, 256, 0, stream>>>(score, newid, sel1, vals1);
    k_pool<1><<<B_ * PB_, 256, 0, stream>>>(bufA, sel1, vals1, part1);

    // ---- stage 2 ----
    k_zero<<<4, 256, 0, stream>>>(bcnt, B_ * CHUNKS_);
    k_bucket<2><<<B_ * SLICES_, 256, 0, stream>>>(src, dst, newid, bcnt, blist);
    k_sort<2><<<B_ * CHUNKS_, 256, 0, stream>>>(bcnt, blist, vals1, csr, ninfo, coef);
    k_agg<true><<<410 * B_, 256, 0, stream>>>(bufA, ninfo, csr, coef, sel1, bufB);
    k_convrow<<<(N2TOT + 255) / 256, 256, 0, stream>>>(bufB, W2, b2, p2, score, N2TOT);
    k_select<2><<<B_, 256, 0, stream>>>(score, nullptr, sel2, vals2);
    k_pool<2><<<B_ * PB_, 256, 0, stream>>>(bufB, sel2, vals2, part2);

    // ---- head (fused combine) ----
    k_head<<<B_, 64, 0, stream>>>(part1, part2, l1w, l1b, l2w, l2b, (float*)d_out);
}

// Round 11
// 421.738 us; speedup vs baseline: 3.7867x; 1.0042x over previous
//
#include <hip/hip_runtime.h>
#include <hip/hip_bf16.h>
#include <cstdint>
#include <cstddef>

#define B_    64
#define N_    2048
#define E_    32768            // edges per graph
#define DIM_  64
#define K1_   1639
#define K2_   1312
#define NTOT  (B_ * N_)        // 131072
#define ETOT  (B_ * E_)        // 2097152
#define N2TOT (B_ * K1_)       // 104896
#define NCLS  6
#define PB_   8                // pooling blocks per graph
#define CHUNKS_ 16             // dst-chunks per graph
#define BCAP  3072             // bucket capacity (mean 2048, sd ~45 -> +22 sigma)
#define SLICES_ 16             // edge slices per graph in k_bucket
#define SCAP  256              // per-slice per-chunk LDS capacity (mean 128, sd ~11)

// ---------------- zero ints ----------------
__global__ void k_zero(int* a, int n) {
    int i = blockIdx.x * 256 + threadIdx.x;
    if (i < n) a[i] = 0;
}

// ---------------- bucket edges by (graph, dst-chunk); packed (dl<<12)|s_local --------------
template<int STAGE>
__launch_bounds__(256)
__global__ void k_bucket(const int* src, const int* dst, const int* remap,
                         int* bcnt, unsigned int* blist) {
    const int LSTR = (STAGE == 1) ? 128 : 103;
    __shared__ unsigned int lb[CHUNKS_][SCAP];
    __shared__ int lc[CHUNKS_], lbase[CHUNKS_];
    int b = blockIdx.x;
    int g = b & 63, slice = b >> 6;
    int tid = threadIdx.x;
    if (tid < CHUNKS_) lc[tid] = 0;
    __syncthreads();
    const int ESL = E_ / SLICES_;              // 2048
    const int* sp = src + (size_t)g * E_ + slice * ESL;
    const int* dp = dst + (size_t)g * E_ + slice * ESL;
    int gbase = g * ((STAGE == 1) ? N_ : K1_);
    for (int e = tid * 4; e < ESL; e += 1024) {
        int4 ss = *(const int4*)&sp[e];
        int4 dd = *(const int4*)&dp[e];
#pragma unroll
        for (int t = 0; t < 4; t++) {
            int s = (&ss.x)[t], d = (&dd.x)[t];
            if (STAGE == 2) {
                s = remap[s]; d = remap[d];
                if ((s | d) < 0) continue;     // edge touches a dropped node
                s -= gbase; d -= gbase;
            } else {
                s &= (N_ - 1); d &= (N_ - 1);
            }
            int ch = d / LSTR;
            int dl = d - ch * LSTR;
            int p = atomicAdd(&lc[ch], 1);
            if (p < SCAP) lb[ch][p] = ((unsigned)dl << 12) | (unsigned)s;
        }
    }
    __syncthreads();
    if (tid < CHUNKS_) lbase[tid] = atomicAdd(&bcnt[g * CHUNKS_ + tid], min(lc[tid], SCAP));
    __syncthreads();
    for (int ch = 0; ch < CHUNKS_; ch++) {
        int n = min(lc[ch], SCAP), base0 = lbase[ch];
        unsigned int* out = blist + (size_t)(g * CHUNKS_ + ch) * BCAP + base0;
        for (int i = tid; i < n; i += 256)
            if (base0 + i < BCAP) out[i] = lb[ch][i];
    }
}

// ---------------- counting-sort bucket by dst -> compact CSR + ninfo + nodeRC ----------------
// nodeRC[node] = (physical_row, coef_bits): stage1 (node, rsq); stage2 (sel[node], vals*rsq).
// This pre-resolves k_agg's per-edge random gathers into ONE 8-B gather per edge.
template<int STAGE>
__launch_bounds__(256)
__global__ void k_sort(const int* bcnt, const unsigned int* blist,
                       const float* vals, const int* sel,
                       unsigned short* csr, int* ninfo, uint2* nodeRC) {
    const int NL   = (STAGE == 1) ? N_ : K1_;
    const int LSTR = (STAGE == 1) ? 128 : 103;
    __shared__ int cnt[128], st[128], cur[128];
    __shared__ unsigned short sorted[BCAP];
    int b = blockIdx.x;
    int g = b & 63, ch = b >> 6;
    int tid = threadIdx.x;
    if (tid < 128) { cnt[tid] = 0; cur[tid] = 0; }
    __syncthreads();
    int n = min(bcnt[g * CHUNKS_ + ch], BCAP);
    const unsigned int* bl = blist + (size_t)(g * CHUNKS_ + ch) * BCAP;
    for (int i = tid; i < n; i += 256) atomicAdd(&cnt[bl[i] >> 12], 1);
    __syncthreads();
    if (tid < 128) st[tid] = cnt[tid];
    __syncthreads();
    for (int o = 1; o < 128; o <<= 1) {        // inclusive scan over 128 counters
        int add = (tid >= o && tid < 128) ? st[tid - o] : 0;
        __syncthreads();
        if (tid < 128) st[tid] += add;
        __syncthreads();
    }
    for (int i = tid; i < n; i += 256) {       // place into sorted order
        unsigned pk = bl[i];
        int dl = (int)(pk >> 12);
        int p = st[dl] - cnt[dl] + atomicAdd(&cur[dl], 1);
        sorted[p] = (unsigned short)(pk & 0xFFFu);
    }
    __syncthreads();
    int cb = (g * CHUNKS_ + ch) * BCAP;
    for (int i = tid; i < n; i += 256) csr[cb + i] = sorted[i];
    int lo = ch * LSTR;
    int nloc = min(LSTR, NL - lo);
    if (tid < nloc) {
        int node = g * NL + lo + tid;
        int c = cnt[tid];
        int start = cb + st[tid] - c;
        ninfo[node] = (start << 8) | min(c, 255);
        float rv = rsqrtf((float)(c + 1));
        uint2 rc;
        if (STAGE == 2) { rc.x = (unsigned)sel[node]; rc.y = __float_as_uint(vals[node] * rv); }
        else            { rc.x = (unsigned)node;      rc.y = __float_as_uint(rv); }
        nodeRC[node] = rc;
    }
}

// ---------------- gather-aggregate, float2 edge-pairing, 8-edge unroll ----------------
// Wave per node. Lanes 0-31 edge i, lanes 32-63 edge i+1; each lane covers 2 features.
// Per edge: ONE 8-B nodeRC gather + ONE 256-B row gather.
template<bool GATE>
__launch_bounds__(256)
__global__ void k_agg(const float* xrows, const int* nodeinfo, const unsigned short* csr,
                      const uint2* nodeRC, float* y) {
    int b = blockIdx.x;
    int xcd = b & 7, r = b >> 3;
    int graph, local;
    if (GATE) {
        graph = xcd * 8 + r / 410;            // ceil(1639/4)=410 blocks/graph
        local = (r % 410) * 4 + (threadIdx.x >> 6);
        if (local >= K1_) return;
    } else {
        graph = xcd * 8 + (r >> 9);           // 512 blocks/graph
        local = (r & 511) * 4 + (threadIdx.x >> 6);
    }
    const int NL = GATE ? K1_ : N_;
    int node = graph * NL + local;
    int lane = threadIdx.x & 63;
    int half = lane >> 5;                      // which edge of the pair
    int fpos = lane & 31;                      // float2 slot within the row
    int ni = nodeinfo[node];
    int cnt = ni & 255, base = ni >> 8;
    float rd = rsqrtf((float)(cnt + 1));
    const float2* x2 = (const float2*)xrows;
    float ax = 0.f, ay = 0.f, bx = 0.f, by = 0.f;
    float cx = 0.f, cy = 0.f, dx = 0.f, dy = 0.f;
    for (int chunk = 0; chunk < cnt; chunk += 64) {
        int nch = min(64, cnt - chunk);
        int sv = 0; float cv = 0.f;
        if (lane < nch) {
            int s = graph * NL + (int)csr[base + chunk + lane];
            uint2 rc = nodeRC[s];
            sv = (int)rc.x;
            cv = __uint_as_float(rc.y);
        }
        int i = 0;
        for (; i + 8 <= nch; i += 8) {         // 8 edges, 4 loads in flight
            int   s0 = __shfl(sv, i + half),     s1 = __shfl(sv, i + 2 + half),
                  s2 = __shfl(sv, i + 4 + half), s3 = __shfl(sv, i + 6 + half);
            float c0 = __shfl(cv, i + half),     c1 = __shfl(cv, i + 2 + half),
                  c2 = __shfl(cv, i + 4 + half), c3 = __shfl(cv, i + 6 + half);
            float2 v0 = x2[(size_t)s0 * 32 + fpos];
            float2 v1 = x2[(size_t)s1 * 32 + fpos];
            float2 v2 = x2[(size_t)s2 * 32 + fpos];
            float2 v3 = x2[(size_t)s3 * 32 + fpos];
            ax += v0.x * c0; ay += v0.y * c0;
            bx += v1.x * c1; by += v1.y * c1;
            cx += v2.x * c2; cy += v2.y * c2;
            dx += v3.x * c3; dy += v3.y * c3;
        }
        for (; i + 4 <= nch; i += 4) {
            int   s0 = __shfl(sv, i + half),  s1 = __shfl(sv, i + 2 + half);
            float c0 = __shfl(cv, i + half),  c1 = __shfl(cv, i + 2 + half);
            float2 v0 = x2[(size_t)s0 * 32 + fpos];
            float2 v1 = x2[(size_t)s1 * 32 + fpos];
            ax += v0.x * c0; ay += v0.y * c0;
            bx += v1.x * c1; by += v1.y * c1;
        }
        for (; i < nch; i += 2) {              // tail pair (possibly half-empty)
            int idx = i + half;
            int   s0 = __shfl(sv, idx & 63);
            float c0 = __shfl(cv, idx & 63);
            if (idx >= nch) c0 = 0.f;
            float2 v0 = x2[(size_t)s0 * 32 + fpos];
            ax += v0.x * c0; ay += v0.y * c0;
        }
    }
    float sx = (ax + bx) + (cx + dx), sy = (ay + by) + (cy + dy);
    sx += __shfl(sx, lane ^ 32);               // combine the two halves
    sy += __shfl(sy, lane ^ 32);
    if (half == 0) {
        uint2 rcs = nodeRC[node];
        float selfc = __uint_as_float(rcs.y);
        float2 sv2 = x2[(size_t)rcs.x * 32 + fpos];
        float2 o;
        o.x = (sx + sv2.x * selfc) * rd;
        o.y = (sy + sv2.y * selfc) * rd;
        ((float2*)y)[(size_t)node * 32 + fpos] = o;
    }
}

// ---------------- fused conv row-matmul + bias + ReLU + score (IN PLACE on y) ---------------
// 128-thread blocks: grid 1024/820 -> ~4 blocks/CU (was 2), better latency hiding.
__launch_bounds__(128)
__global__ void k_convrow(float* y, const float* W, const float* bias, const float* pvec,
                          float* score, int rows) {
    __shared__ float Wl[DIM_ * DIM_];
    __shared__ float bl[DIM_], pl[DIM_];
    __shared__ float rpn;
    int tid = threadIdx.x;
    for (int i = tid; i < DIM_ * DIM_; i += 128) Wl[i] = W[i];
    if (tid < DIM_) { bl[tid] = bias[tid]; pl[tid] = pvec[tid]; }
    __syncthreads();
    if (tid == 0) {
        float s = 0.0f;
        for (int i = 0; i < DIM_; i++) s += pl[i] * pl[i];
        rpn = rsqrtf(s);
    }
    __syncthreads();
    int row = blockIdx.x * 128 + tid;
    if (row >= rows) return;
    float r[DIM_];
    float4* yp = (float4*)(y + (size_t)row * DIM_);
#pragma unroll
    for (int v = 0; v < 16; v++) {
        float4 q = yp[v];
        r[4*v] = q.x; r[4*v+1] = q.y; r[4*v+2] = q.z; r[4*v+3] = q.w;
    }
    float4 a[16];
    float dot = 0.0f;
#pragma unroll
    for (int jb = 0; jb < 16; jb++) {
        float4 acc = make_float4(bl[jb*4], bl[jb*4+1], bl[jb*4+2], bl[jb*4+3]);
#pragma unroll
        for (int i = 0; i < DIM_; i++) {
            float4 w4 = *(const float4*)&Wl[i * DIM_ + jb * 4];
            acc.x += r[i] * w4.x; acc.y += r[i] * w4.y;
            acc.z += r[i] * w4.z; acc.w += r[i] * w4.w;
        }
        acc.x = fmaxf(acc.x, 0.f); acc.y = fmaxf(acc.y, 0.f);
        acc.z = fmaxf(acc.z, 0.f); acc.w = fmaxf(acc.w, 0.f);
        dot += acc.x * pl[jb*4] + acc.y * pl[jb*4+1] + acc.z * pl[jb*4+2] + acc.w * pl[jb*4+3];
        a[jb] = acc;
    }
#pragma unroll
    for (int jb = 0; jb < 16; jb++) yp[jb] = a[jb];
    score[row] = tanhf(dot * rpn);
}

// ---------------- exact top-K: 6-pass radix select, parallel suffix-sum bin scan ------------
template<int STAGE>
__launch_bounds__(256)
__global__ void k_select(const float* score, int* new_id, int* sel, float* vals) {
    const int Nin = (STAGE == 1) ? N_ : K1_;
    const int K   = (STAGE == 1) ? K1_ : K2_;
    __shared__ unsigned long long keys[N_];
    __shared__ int bins[256], ts[256];
    __shared__ unsigned long long s_prefix;
    __shared__ int s_need, s_cnt;
    int g = blockIdx.x, tid = threadIdx.x;
    const float* sg = score + (size_t)g * Nin;
    for (int i = tid; i < Nin; i += 256) {
        unsigned u = __float_as_uint(sg[i]);
        u = (u & 0x80000000u) ? ~u : (u | 0x80000000u);
        keys[i] = ((unsigned long long)u << 11) | (unsigned long long)(2047 - i);
    }
    if (tid == 0) { s_need = K; s_prefix = 0ull; s_cnt = 0; }
    __syncthreads();
    for (int shift = 40; shift >= 0; shift -= 8) {
        bins[tid] = 0;
        __syncthreads();
        unsigned long long pref = s_prefix;
        int need = s_need;
        int hi = shift + 8;
        for (int i = tid; i < Nin; i += 256) {
            unsigned long long k = keys[i];
            if ((k >> hi) == pref) atomicAdd(&bins[(int)((k >> shift) & 255)], 1);
        }
        __syncthreads();
        ts[tid] = bins[tid];
        __syncthreads();
        for (int o = 1; o < 256; o <<= 1) {
            int add = (tid + o < 256) ? ts[tid + o] : 0;
            __syncthreads();
            ts[tid] += add;
            __syncthreads();
        }
        int nxt = (tid == 255) ? 0 : ts[tid + 1];
        if (ts[tid] >= need && nxt < need) {
            s_prefix = (pref << 8) | (unsigned long long)tid;
            s_need = need - nxt;
        }
        __syncthreads();
    }
    unsigned long long T = s_prefix;
    for (int i = tid; i < Nin; i += 256) {
        if (keys[i] >= T) {
            int r = atomicAdd(&s_cnt, 1);
            int slot = g * K + r;
            sel[slot]  = g * Nin + i;
            vals[slot] = sg[i];
            if (STAGE == 1) new_id[g * N_ + i] = slot;
        } else if (STAGE == 1) {
            new_id[g * N_ + i] = -1;
        }
    }
}

// ---------------- gated max/mean pooling, PB_ blocks per graph ----------------
template<int STAGE>
__launch_bounds__(256)
__global__ void k_pool(const float* conv, const int* sel, const float* vals, float* part) {
    const int K = (STAGE == 1) ? K1_ : K2_;
    int b = blockIdx.x;
    int g = b & 63, c = b >> 6;
    int wv = threadIdx.x >> 6, lane = threadIdx.x & 63;
    float mx = -3.402823466e38f, sm = 0.f;
    for (int r = c * 4 + wv; r < K; r += PB_ * 4) {
        int slot = g * K + r;
        int row  = sel[slot];
        float val = vals[slot];
        float v = conv[(size_t)row * DIM_ + lane] * val;
        mx = fmaxf(mx, v);
        sm += v;
    }
    __shared__ float rmx[4][64], rsm[4][64];
    rmx[wv][lane] = mx; rsm[wv][lane] = sm;
    __syncthreads();
    if (wv == 0) {
        mx = fmaxf(fmaxf(rmx[0][lane], rmx[1][lane]), fmaxf(rmx[2][lane], rmx[3][lane]));
        sm = rsm[0][lane] + rsm[1][lane] + rsm[2][lane] + rsm[3][lane];
        part[((size_t)(g * PB_ + c) * 2 + 0) * 64 + lane] = mx;
        part[((size_t)(g * PB_ + c) * 2 + 1) * 64 + lane] = sm;
    }
}

// ---------------- MLP head (fused partial-combine for both stages) ----------------
__launch_bounds__(64)
__global__ void k_head(const float* part1, const float* part2,
                       const float* l1w, const float* l1b,
                       const float* l2w, const float* l2b, float* out) {
    __shared__ float h[128];
    __shared__ float h1[64];
    int g = blockIdx.x, t = threadIdx.x;
    float mx1 = -3.402823466e38f, sm1 = 0.f, mx2 = -3.402823466e38f, sm2 = 0.f;
#pragma unroll
    for (int c = 0; c < PB_; c++) {
        mx1 = fmaxf(mx1, part1[((size_t)(g * PB_ + c) * 2 + 0) * 64 + t]);
        sm1 += part1[((size_t)(g * PB_ + c) * 2 + 1) * 64 + t];
        mx2 = fmaxf(mx2, part2[((size_t)(g * PB_ + c) * 2 + 0) * 64 + t]);
        sm2 += part2[((size_t)(g * PB_ + c) * 2 + 1) * 64 + t];
    }
    h[t]      = mx1 + mx2;
    h[t + 64] = sm1 / (float)K1_ + sm2 / (float)K2_;
    __syncthreads();
    float acc = l1b[t];
#pragma unroll 8
    for (int i = 0; i < 128; i++) acc += h[i] * l1w[i * 64 + t];
    h1[t] = fmaxf(acc, 0.0f);
    __syncthreads();
    if (t < NCLS) {
        float o = l2b[t];
#pragma unroll
        for (int i = 0; i < 64; i++) o += h1[i] * l2w[i * NCLS + t];
        out[g * NCLS + t] = o;
    }
}

extern "C" void kernel_launch(void* const* d_in, const int* in_sizes, int n_in,
                              void* d_out, int out_size, void* d_ws, size_t ws_size,
                              hipStream_t stream) {
    const float* x   = (const float*)d_in[0];
    const int*   ei  = (const int*)d_in[1];
    const int*   src = ei;
    const int*   dst = ei + ETOT;
    const float* W1  = (const float*)d_in[3];
    const float* b1  = (const float*)d_in[4];
    const float* p1  = (const float*)d_in[5];
    const float* W2  = (const float*)d_in[6];
    const float* b2  = (const float*)d_in[7];
    const float* p2  = (const float*)d_in[8];
    const float* l1w = (const float*)d_in[9];
    const float* l1b = (const float*)d_in[10];
    const float* l2w = (const float*)d_in[11];
    const float* l2b = (const float*)d_in[12];
    (void)in_sizes; (void)n_in; (void)out_size; (void)ws_size;

    // workspace layout (~85 MB)
    char* ws = (char*)d_ws;
    size_t off = 0;
    auto alloc = [&](size_t bytes) -> void* {
        void* p = ws + off;
        off = (off + bytes + 255) & ~(size_t)255;
        return p;
    };
    float*          bufA   = (float*)         alloc((size_t)NTOT  * DIM_ * 4); // y1 -> conv1
    float*          bufB   = (float*)         alloc((size_t)N2TOT * DIM_ * 4); // y2 -> conv2
    unsigned int*   blist  = (unsigned int*)  alloc((size_t)B_ * CHUNKS_ * BCAP * 4); // 12.6 MB
    unsigned short* csr    = (unsigned short*)alloc((size_t)B_ * CHUNKS_ * BCAP * 2); // 6.3 MB
    int*            bcnt   = (int*)           alloc((size_t)B_ * CHUNKS_ * 4);
    int*            ninfo  = (int*)           alloc((size_t)NTOT * 4);
    uint2*          nodeRC = (uint2*)         alloc((size_t)NTOT * 8);
    float*          score  = (float*)         alloc((size_t)NTOT * 4);
    int*            newid  = (int*)           alloc((size_t)NTOT * 4);
    int*            sel1   = (int*)           alloc((size_t)N2TOT * 4);
    float*          vals1  = (float*)         alloc((size_t)N2TOT * 4);
    int*            sel2   = (int*)           alloc((size_t)B_ * K2_ * 4);
    float*          vals2  = (float*)         alloc((size_t)B_ * K2_ * 4);
    float*          part1  = (float*)         alloc((size_t)B_ * PB_ * 128 * 4);
    float*          part2  = (float*)         alloc((size_t)B_ * PB_ * 128 * 4);

    // ---- stage 1 ----
    k_zero<<<4, 256, 0, stream>>>(bcnt, B_ * CHUNKS_);
    k_bucket<1><<<B_ * SLICES_, 256, 0, stream>>>(src, dst, nullptr, bcnt, blist);
    k_sort<1><<<B_ * CHUNKS_, 256, 0, stream>>>(bcnt, blist, nullptr, nullptr, csr, ninfo, nodeRC);
    k_agg<false><<<NTOT / 4, 256, 0, stream>>>(x, ninfo, csr, nodeRC, bufA);
    k_convrow<<<NTOT / 128, 128, 0, stream>>>(bufA, W1, b1, p1, score, NTOT);
    k_select<1><<<B_, 256, 0, stream>>>(score, newid, sel1, vals1);
    k_pool<1><<<B_ * PB_, 256, 0, stream>>>(bufA, sel1, vals1, part1);

    // ---- stage 2 ----
    k_zero<<<4, 256, 0, stream>>>(bcnt, B_ * CHUNKS_);
    k_bucket<2><<<B_ * SLICES_, 256, 0, stream>>>(src, dst, newid, bcnt, blist);
    k_sort<2><<<B_ * CHUNKS_, 256, 0, stream>>>(bcnt, blist, vals1, sel1, csr, ninfo, nodeRC);
    k_agg<true><<<410 * B_, 256, 0, stream>>>(bufA, ninfo, csr, nodeRC, bufB);
    k_convrow<<<(N2TOT + 127) / 128, 128, 0, stream>>>(bufB, W2, b2, p2, score, N2TOT);
    k_select<2><<<B_, 256, 0, stream>>>(score, nullptr, sel2, vals2);
    k_pool<2><<<B_ * PB_, 256, 0, stream>>>(bufB, sel2, vals2, part2);

    // ---- head (fused combine) ----
    k_head<<<B_, 64, 0, stream>>>(part1, part2, l1w, l1b, l2w, l2b, (float*)d_out);
}